// Round 1
// baseline (410.113 us; speedup 1.0000x reference)
//
#include <hip/hip_runtime.h>

#define Bx 16
#define Gx 128
#define Nx 512
#define Px 4
#define Kx 3
#define Fx 128
#define NEG_SLOPE 0.2f
#define INF_NUM 1.0e12f
#define ZERO_TOL 1e-9f

// ---------------------------------------------------------------------------
// K1: Wx[b,p,g,n] = sum_h W[p,g,h] * x[b,h,n]
// grid (B*P, N/64), block 256. Tile: 128 rows (all g) x 64 cols, K=128.
// ---------------------------------------------------------------------------
__global__ __launch_bounds__(256) void wx_kernel(const float* __restrict__ x,
                                                 const float* __restrict__ W,
                                                 float* __restrict__ Wx) {
  const int bp = blockIdx.x;
  const int b = bp / Px, p = bp % Px;
  const int n0 = blockIdx.y * 64;
  const int tid = threadIdx.x;
  __shared__ float Wt[Gx][132];  // Wt[h][g] (transposed)
  __shared__ float xs[Gx][64];   // xs[h][c]

  const float* Wp = W + p * Gx * Gx;
  for (int t = tid; t < (Gx * Gx) / 4; t += 256) {
    int g = t >> 5, hq = t & 31;
    float4 v = *(const float4*)&Wp[g * Gx + hq * 4];
    Wt[hq * 4 + 0][g] = v.x;
    Wt[hq * 4 + 1][g] = v.y;
    Wt[hq * 4 + 2][g] = v.z;
    Wt[hq * 4 + 3][g] = v.w;
  }
  const float* xb = x + b * Gx * Nx + n0;
  for (int t = tid; t < (Gx * 64) / 4; t += 256) {
    int h = t >> 4, c4 = t & 15;
    *(float4*)&xs[h][c4 * 4] = *(const float4*)&xb[h * Nx + c4 * 4];
  }
  __syncthreads();

  const int rg = tid >> 3;  // 0..31
  const int cg = tid & 7;   // 0..7
  const int r0 = rg * 4, c0 = cg * 8;
  float acc[4][8];
#pragma unroll
  for (int i = 0; i < 4; i++)
#pragma unroll
    for (int j = 0; j < 8; j++) acc[i][j] = 0.f;

#pragma unroll 4
  for (int h = 0; h < Gx; h++) {
    float4 wv = *(const float4*)&Wt[h][r0];
    float4 x0 = *(const float4*)&xs[h][c0];
    float4 x1 = *(const float4*)&xs[h][c0 + 4];
    float av[4] = {wv.x, wv.y, wv.z, wv.w};
    float bv[8] = {x0.x, x0.y, x0.z, x0.w, x1.x, x1.y, x1.z, x1.w};
#pragma unroll
    for (int i = 0; i < 4; i++)
#pragma unroll
      for (int j = 0; j < 8; j++) acc[i][j] = fmaf(av[i], bv[j], acc[i][j]);
  }

  float* Wxp = Wx + (size_t)bp * Gx * Nx + n0;
#pragma unroll
  for (int i = 0; i < 4; i++) {
    float4 o0 = {acc[i][0], acc[i][1], acc[i][2], acc[i][3]};
    float4 o1 = {acc[i][4], acc[i][5], acc[i][6], acc[i][7]};
    *(float4*)&Wxp[(r0 + i) * Nx + c0] = o0;
    *(float4*)&Wxp[(r0 + i) * Nx + c0 + 4] = o1;
  }
}

// ---------------------------------------------------------------------------
// K2: xWx[m,n] = sum_g x[b,g,m]*Wx[b,p,g,n]; leaky-relu, mask by |S|>tol,
// row-softmax, * mask -> aij[b,p,m,n].
// grid (B*P, N/16), block 256 (4 waves). Each wave owns 4 rows x 512 cols.
// ---------------------------------------------------------------------------
__global__ __launch_bounds__(256) void attn_kernel(const float* __restrict__ x,
                                                   const float* __restrict__ S,
                                                   const float* __restrict__ Wx,
                                                   float* __restrict__ aij) {
  const int bp = blockIdx.x;
  const int b = bp / Px;
  const int m0 = blockIdx.y * 16;
  const int tid = threadIdx.x;
  __shared__ float xt[Gx][16];    // xt[g][r] = x[b,g,m0+r]
  __shared__ float Wxs[32][Nx];   // K-chunk of Wx

  const float* xb = x + b * Gx * Nx;
  for (int t = tid; t < Gx * 16; t += 256) {
    int g = t >> 4, r = t & 15;
    xt[g][r] = xb[g * Nx + m0 + r];
  }

  const int wv = tid >> 6;  // wave id: row group 0..3
  const int ln = tid & 63;
  const int c0 = ln * 8;
  float acc[4][8];
#pragma unroll
  for (int i = 0; i < 4; i++)
#pragma unroll
    for (int j = 0; j < 8; j++) acc[i][j] = 0.f;

  const float* Wxp = Wx + (size_t)bp * Gx * Nx;
  for (int g0 = 0; g0 < Gx; g0 += 32) {
    __syncthreads();
    for (int t = tid; t < 32 * (Nx / 4); t += 256) {
      int row = t >> 7, c4 = t & 127;
      *(float4*)&Wxs[row][c4 * 4] = *(const float4*)&Wxp[(g0 + row) * Nx + c4 * 4];
    }
    __syncthreads();
#pragma unroll 4
    for (int g = 0; g < 32; g++) {
      float4 xv = *(const float4*)&xt[g0 + g][wv * 4];
      float4 w0 = *(const float4*)&Wxs[g][c0];
      float4 w1 = *(const float4*)&Wxs[g][c0 + 4];
      float av[4] = {xv.x, xv.y, xv.z, xv.w};
      float bv[8] = {w0.x, w0.y, w0.z, w0.w, w1.x, w1.y, w1.z, w1.w};
#pragma unroll
      for (int i = 0; i < 4; i++)
#pragma unroll
        for (int j = 0; j < 8; j++) acc[i][j] = fmaf(av[i], bv[j], acc[i][j]);
    }
  }

  // epilogue: mask + leaky relu + softmax per row (rows live within one wave)
  const float* Sb = S + (size_t)b * Nx * Nx;
  float* ap = aij + (size_t)bp * Nx * Nx;
#pragma unroll
  for (int i = 0; i < 4; i++) {
    int m = m0 + wv * 4 + i;
    const float* Srow = Sb + (size_t)m * Nx + c0;
    float4 s0 = *(const float4*)&Srow[0];
    float4 s1 = *(const float4*)&Srow[4];
    float Svals[8] = {s0.x, s0.y, s0.z, s0.w, s1.x, s1.y, s1.z, s1.w};
    float sc[8];
    int mk[8];
    float rmax = -INF_NUM;
#pragma unroll
    for (int j = 0; j < 8; j++) {
      mk[j] = fabsf(Svals[j]) > ZERO_TOL;
      float v = acc[i][j];
      float l = v >= 0.f ? v : NEG_SLOPE * v;
      sc[j] = mk[j] ? l : -INF_NUM;
      rmax = fmaxf(rmax, sc[j]);
    }
#pragma unroll
    for (int off = 32; off >= 1; off >>= 1)
      rmax = fmaxf(rmax, __shfl_xor(rmax, off, 64));
    float rsum = 0.f;
#pragma unroll
    for (int j = 0; j < 8; j++) {
      sc[j] = mk[j] ? __expf(sc[j] - rmax) : 0.f;
      rsum += sc[j];
    }
#pragma unroll
    for (int off = 32; off >= 1; off >>= 1) rsum += __shfl_xor(rsum, off, 64);
    float inv = rsum > 0.f ? 1.f / rsum : 0.f;
    float4 o0 = {sc[0] * inv, sc[1] * inv, sc[2] * inv, sc[3] * inv};
    float4 o1 = {sc[4] * inv, sc[5] * inv, sc[6] * inv, sc[7] * inv};
    *(float4*)&ap[(size_t)m * Nx + c0] = o0;
    *(float4*)&ap[(size_t)m * Nx + c0 + 4] = o1;
  }
}

// ---------------------------------------------------------------------------
// K3: C[bp,g,m] = sum_n A[g,n] * aij[bp,n,m].  A = x[b] (APB=0) or z1[bp] (=1)
// grid (B*P, N/128), block 256, tile 128x128, BK=16, 8x8 per thread.
// ---------------------------------------------------------------------------
template <int APB>
__global__ __launch_bounds__(256) void hop_kernel(const float* __restrict__ Asrc,
                                                  const float* __restrict__ aij,
                                                  float* __restrict__ C) {
  const int bp = blockIdx.x;
  const int b = bp / Px;
  const int n0c = blockIdx.y * 128;
  const int tid = threadIdx.x;
  __shared__ float As[16][132];  // As[k][g] transposed chunk
  __shared__ float Bs[16][128];

  const float* A = Asrc + (size_t)(APB ? bp : b) * Gx * Nx;
  const float* Bp = aij + (size_t)bp * Nx * Nx;
  const int r0 = (tid >> 4) * 8;
  const int c0 = (tid & 15) * 8;
  float acc[8][8];
#pragma unroll
  for (int i = 0; i < 8; i++)
#pragma unroll
    for (int j = 0; j < 8; j++) acc[i][j] = 0.f;

  for (int k0 = 0; k0 < Nx; k0 += 16) {
    __syncthreads();
    for (int t = tid; t < 512; t += 256) {
      int r = t >> 2, kq = t & 3;
      float4 v = *(const float4*)&A[r * Nx + k0 + kq * 4];
      As[kq * 4 + 0][r] = v.x;
      As[kq * 4 + 1][r] = v.y;
      As[kq * 4 + 2][r] = v.z;
      As[kq * 4 + 3][r] = v.w;
    }
    for (int t = tid; t < 512; t += 256) {
      int k = t >> 5, c4 = t & 31;
      *(float4*)&Bs[k][c4 * 4] = *(const float4*)&Bp[(size_t)(k0 + k) * Nx + n0c + c4 * 4];
    }
    __syncthreads();
#pragma unroll
    for (int k = 0; k < 16; k++) {
      float4 a0 = *(const float4*)&As[k][r0];
      float4 a1 = *(const float4*)&As[k][r0 + 4];
      float4 b0 = *(const float4*)&Bs[k][c0];
      float4 b1 = *(const float4*)&Bs[k][c0 + 4];
      float av[8] = {a0.x, a0.y, a0.z, a0.w, a1.x, a1.y, a1.z, a1.w};
      float bv[8] = {b0.x, b0.y, b0.z, b0.w, b1.x, b1.y, b1.z, b1.w};
#pragma unroll
      for (int i = 0; i < 8; i++)
#pragma unroll
        for (int j = 0; j < 8; j++) acc[i][j] = fmaf(av[i], bv[j], acc[i][j]);
    }
  }

  float* Cp = C + (size_t)bp * Gx * Nx + n0c;
#pragma unroll
  for (int i = 0; i < 8; i++) {
    float4 o0 = {acc[i][0], acc[i][1], acc[i][2], acc[i][3]};
    float4 o1 = {acc[i][4], acc[i][5], acc[i][6], acc[i][7]};
    *(float4*)&Cp[(r0 + i) * Nx + c0] = o0;
    *(float4*)&Cp[(r0 + i) * Nx + c0 + 4] = o1;
  }
}

// ---------------------------------------------------------------------------
// K4: y[b,p,f,n] = relu( sum_{k,g} h[p,f,k,g]*Z[k,g,n] + bias[f] )
// Z rows: [x[b]; z1[bp]; z2[bp]].  out[b, p*F+f, n].
// grid (B*P, N/128), block 256, tile 128x128, K=384, BK=16.
// ---------------------------------------------------------------------------
__global__ __launch_bounds__(256) void filt_kernel(const float* __restrict__ x,
                                                   const float* __restrict__ z1,
                                                   const float* __restrict__ z2,
                                                   const float* __restrict__ h,
                                                   const float* __restrict__ bias,
                                                   float* __restrict__ out) {
  const int bp = blockIdx.x;
  const int b = bp / Px, p = bp % Px;
  const int n0c = blockIdx.y * 128;
  const int tid = threadIdx.x;
  __shared__ float As[16][132];  // As[k][f]
  __shared__ float Bs[16][128];

  const float* H = h + (size_t)p * Fx * (Kx * Gx);
  const int r0 = (tid >> 4) * 8;
  const int c0 = (tid & 15) * 8;
  float acc[8][8];
#pragma unroll
  for (int i = 0; i < 8; i++)
#pragma unroll
    for (int j = 0; j < 8; j++) acc[i][j] = 0.f;

  for (int k0 = 0; k0 < Kx * Gx; k0 += 16) {
    int seg = k0 >> 7;
    int kin = k0 & 127;
    const float* Zseg;
    if (seg == 0)
      Zseg = x + (size_t)b * Gx * Nx + (size_t)kin * Nx;
    else if (seg == 1)
      Zseg = z1 + (size_t)bp * Gx * Nx + (size_t)kin * Nx;
    else
      Zseg = z2 + (size_t)bp * Gx * Nx + (size_t)kin * Nx;
    __syncthreads();
    for (int t = tid; t < 512; t += 256) {
      int f = t >> 2, kq = t & 3;
      float4 v = *(const float4*)&H[(size_t)f * (Kx * Gx) + k0 + kq * 4];
      As[kq * 4 + 0][f] = v.x;
      As[kq * 4 + 1][f] = v.y;
      As[kq * 4 + 2][f] = v.z;
      As[kq * 4 + 3][f] = v.w;
    }
    for (int t = tid; t < 512; t += 256) {
      int k = t >> 5, c4 = t & 31;
      *(float4*)&Bs[k][c4 * 4] = *(const float4*)&Zseg[(size_t)k * Nx + n0c + c4 * 4];
    }
    __syncthreads();
#pragma unroll
    for (int k = 0; k < 16; k++) {
      float4 a0 = *(const float4*)&As[k][r0];
      float4 a1 = *(const float4*)&As[k][r0 + 4];
      float4 b0 = *(const float4*)&Bs[k][c0];
      float4 b1 = *(const float4*)&Bs[k][c0 + 4];
      float av[8] = {a0.x, a0.y, a0.z, a0.w, a1.x, a1.y, a1.z, a1.w};
      float bv[8] = {b0.x, b0.y, b0.z, b0.w, b1.x, b1.y, b1.z, b1.w};
#pragma unroll
      for (int i = 0; i < 8; i++)
#pragma unroll
        for (int j = 0; j < 8; j++) acc[i][j] = fmaf(av[i], bv[j], acc[i][j]);
    }
  }

  float* op = out + ((size_t)b * (Px * Fx) + (size_t)p * Fx) * Nx + n0c;
#pragma unroll
  for (int i = 0; i < 8; i++) {
    float bi = bias[r0 + i];
    float o[8];
#pragma unroll
    for (int j = 0; j < 8; j++) {
      float v = acc[i][j] + bi;
      o[j] = v > 0.f ? v : 0.f;
    }
    float4 o0 = {o[0], o[1], o[2], o[3]};
    float4 o1 = {o[4], o[5], o[6], o[7]};
    *(float4*)&op[(size_t)(r0 + i) * Nx + c0] = o0;
    *(float4*)&op[(size_t)(r0 + i) * Nx + c0 + 4] = o1;
  }
}

// ---------------------------------------------------------------------------
extern "C" void kernel_launch(void* const* d_in, const int* in_sizes, int n_in,
                              void* d_out, int out_size, void* d_ws, size_t ws_size,
                              hipStream_t stream) {
  const float* x = (const float*)d_in[0];     // (B,G,N)
  const float* S = (const float*)d_in[1];     // (B,1,N,N)
  const float* W = (const float*)d_in[2];     // (P,1,G,G)
  // d_in[3] = mixer (unused in key-query mode)
  const float* h = (const float*)d_in[4];     // (P,F,1,K,G)
  const float* bias = (const float*)d_in[5];  // (F,1)
  float* out = (float*)d_out;

  float* ws = (float*)d_ws;
  float* Wx = ws;                                  // B*P*G*N  = 4,194,304
  float* aij = Wx + (size_t)Bx * Px * Gx * Nx;     // B*P*N*N  = 16,777,216
  float* z1 = aij + (size_t)Bx * Px * Nx * Nx;     // B*P*G*N
  float* z2 = z1 + (size_t)Bx * Px * Gx * Nx;      // B*P*G*N

  wx_kernel<<<dim3(Bx * Px, Nx / 64), 256, 0, stream>>>(x, W, Wx);
  attn_kernel<<<dim3(Bx * Px, Nx / 16), 256, 0, stream>>>(x, S, Wx, aij);
  hop_kernel<0><<<dim3(Bx * Px, Nx / 128), 256, 0, stream>>>(x, aij, z1);
  hop_kernel<1><<<dim3(Bx * Px, Nx / 128), 256, 0, stream>>>(z1, aij, z2);
  filt_kernel<<<dim3(Bx * Px, Nx / 128), 256, 0, stream>>>(x, z1, z2, h, bias, out);
  (void)in_sizes; (void)n_in; (void)out_size; (void)ws_size;
}

// Round 2
// 152.506 us; speedup vs baseline: 2.6892x; 2.6892x over previous
//
#include <hip/hip_runtime.h>

#define Bx 16
#define Gx 128
#define Nx 512
#define Px 4
#define Kx 3
#define Fx 128
#define NEG_SLOPE 0.2f
#define INF_NUM 1.0e12f
#define ZERO_TOL 1e-9f

typedef unsigned short u16;
typedef unsigned int u32;
typedef __bf16 v8bf __attribute__((ext_vector_type(8)));
typedef float v4f __attribute__((ext_vector_type(4)));

__device__ __forceinline__ u16 f2b(float f) {
  union { float f; u32 u; } v; v.f = f;
  u32 r = (v.u + 0x7fffu + ((v.u >> 16) & 1u)) >> 16;
  return (u16)r;
}

// async global->LDS, 16B per lane; dst must be wave-uniform base (lane*16 auto)
#define G2L16(gsrc, ldst)                                                     \
  __builtin_amdgcn_global_load_lds(                                           \
      (const __attribute__((address_space(1))) void*)(gsrc),                  \
      (__attribute__((address_space(3))) void*)(ldst), 16, 0, 0)

// ---------------------------------------------------------------------------
// cast x -> xb (bf16, [b][g][n]) and xTb (bf16, [b][n][g])
// grid (G/32, N/32, B), 256 thr
// ---------------------------------------------------------------------------
__global__ __launch_bounds__(256) void castx_kernel(const float* __restrict__ x,
                                                    u16* __restrict__ xb,
                                                    u16* __restrict__ xTb) {
  const int b = blockIdx.z, g0 = blockIdx.x * 32, n0 = blockIdx.y * 32;
  const int tid = threadIdx.x;
  __shared__ float t[32][33];
  const int r = tid >> 3, c4 = (tid & 7) * 4;
  const float* xp = x + (size_t)b * Gx * Nx;
  float4 v = *(const float4*)&xp[(g0 + r) * Nx + n0 + c4];
  ushort4 o;
  o.x = f2b(v.x); o.y = f2b(v.y); o.z = f2b(v.z); o.w = f2b(v.w);
  *(ushort4*)&xb[(size_t)b * Gx * Nx + (g0 + r) * Nx + n0 + c4] = o;
  t[r][c4 + 0] = v.x; t[r][c4 + 1] = v.y; t[r][c4 + 2] = v.z; t[r][c4 + 3] = v.w;
  __syncthreads();
  ushort4 o2;
  o2.x = f2b(t[c4 + 0][r]);
  o2.y = f2b(t[c4 + 1][r]);
  o2.z = f2b(t[c4 + 2][r]);
  o2.w = f2b(t[c4 + 3][r]);
  *(ushort4*)&xTb[(size_t)b * Nx * Gx + (n0 + r) * Gx + g0 + c4] = o2;
}

// cast h (P,F,K,G) flat -> bf16
__global__ __launch_bounds__(256) void casth_kernel(const float* __restrict__ h,
                                                    u16* __restrict__ Hb) {
  int i4 = (blockIdx.x * 256 + threadIdx.x) * 4;
  float4 v = *(const float4*)&h[i4];
  ushort4 o;
  o.x = f2b(v.x); o.y = f2b(v.y); o.z = f2b(v.z); o.w = f2b(v.w);
  *(ushort4*)&Hb[i4] = o;
}

// ---------------------------------------------------------------------------
// K1: Wx[b,p,g,n] = sum_h W[p,g,h] * x[b,h,n]   (fp32, unchanged)
// ---------------------------------------------------------------------------
__global__ __launch_bounds__(256) void wx_kernel(const float* __restrict__ x,
                                                 const float* __restrict__ W,
                                                 float* __restrict__ Wx) {
  const int bp = blockIdx.x;
  const int b = bp / Px, p = bp % Px;
  const int n0 = blockIdx.y * 64;
  const int tid = threadIdx.x;
  __shared__ float Wt[Gx][132];
  __shared__ float xs[Gx][64];

  const float* Wp = W + p * Gx * Gx;
  for (int t = tid; t < (Gx * Gx) / 4; t += 256) {
    int g = t >> 5, hq = t & 31;
    float4 v = *(const float4*)&Wp[g * Gx + hq * 4];
    Wt[hq * 4 + 0][g] = v.x;
    Wt[hq * 4 + 1][g] = v.y;
    Wt[hq * 4 + 2][g] = v.z;
    Wt[hq * 4 + 3][g] = v.w;
  }
  const float* xb = x + b * Gx * Nx + n0;
  for (int t = tid; t < (Gx * 64) / 4; t += 256) {
    int hh = t >> 4, c4 = t & 15;
    *(float4*)&xs[hh][c4 * 4] = *(const float4*)&xb[hh * Nx + c4 * 4];
  }
  __syncthreads();

  const int r0 = (tid >> 3) * 4, c0 = (tid & 7) * 8;
  float acc[4][8];
#pragma unroll
  for (int i = 0; i < 4; i++)
#pragma unroll
    for (int j = 0; j < 8; j++) acc[i][j] = 0.f;

#pragma unroll 4
  for (int hh = 0; hh < Gx; hh++) {
    float4 wv = *(const float4*)&Wt[hh][r0];
    float4 x0 = *(const float4*)&xs[hh][c0];
    float4 x1 = *(const float4*)&xs[hh][c0 + 4];
    float av[4] = {wv.x, wv.y, wv.z, wv.w};
    float bv[8] = {x0.x, x0.y, x0.z, x0.w, x1.x, x1.y, x1.z, x1.w};
#pragma unroll
    for (int i = 0; i < 4; i++)
#pragma unroll
      for (int j = 0; j < 8; j++) acc[i][j] = fmaf(av[i], bv[j], acc[i][j]);
  }

  float* Wxp = Wx + (size_t)bp * Gx * Nx + n0;
#pragma unroll
  for (int i = 0; i < 4; i++) {
    float4 o0 = {acc[i][0], acc[i][1], acc[i][2], acc[i][3]};
    float4 o1 = {acc[i][4], acc[i][5], acc[i][6], acc[i][7]};
    *(float4*)&Wxp[(r0 + i) * Nx + c0] = o0;
    *(float4*)&Wxp[(r0 + i) * Nx + c0 + 4] = o1;
  }
}

// ---------------------------------------------------------------------------
// K2: scores[i][j] = leakyrelu(sum_g x[g,i]*Wx[g,j]); mask; softmax over j;
// write aijT[j][i] (bf16).  grid (B*P, N/32), 256 thr (4 waves x 8 rows).
// LDS: xt[128][32] f32 (16KB) + union{ Wxs[16][512] f32 (32KB) | T[512][34] bf16 }
// ---------------------------------------------------------------------------
__global__ __launch_bounds__(256) void attn2_kernel(const float* __restrict__ x,
                                                    const float* __restrict__ S,
                                                    const float* __restrict__ Wx,
                                                    u16* __restrict__ aijT) {
  __shared__ __align__(16) char smem[16384 + 34816];
  float* xt = (float*)smem;              // [128][32]
  float* Wxs = (float*)(smem + 16384);   // [16][512]
  const int bp = blockIdx.x;
  const int b = bp >> 2;
  const int i0 = blockIdx.y * 32;
  const int tid = threadIdx.x;
  const int w = tid >> 6, ln = tid & 63;

  // stage xt[g][ii] = x[b][g][i0+ii]
  const float* xp = x + (size_t)b * Gx * Nx;
  for (int q = tid; q < 1024; q += 256) {
    int g = q >> 3, c4 = (q & 7) * 4;
    *(float4*)&xt[g * 32 + c4] = *(const float4*)&xp[g * Nx + i0 + c4];
  }

  float acc[8][8];
#pragma unroll
  for (int i = 0; i < 8; i++)
#pragma unroll
    for (int j = 0; j < 8; j++) acc[i][j] = 0.f;

  const float* Wxp = Wx + (size_t)bp * Gx * Nx;
  for (int g0 = 0; g0 < Gx; g0 += 16) {
    __syncthreads();
    for (int q = tid; q < 2048; q += 256) {
      int row = q >> 7, c4 = (q & 127) * 4;
      *(float4*)&Wxs[row * Nx + c4] = *(const float4*)&Wxp[(g0 + row) * Nx + c4];
    }
    __syncthreads();
#pragma unroll 2
    for (int gg = 0; gg < 16; gg++) {
      const float* xrow = &xt[(g0 + gg) * 32];
      float4 a0 = *(const float4*)&xrow[w * 8];
      float4 a1 = *(const float4*)&xrow[w * 8 + 4];
      const float* wrow = &Wxs[gg * Nx];
      float4 b0 = *(const float4*)&wrow[ln * 4];
      float4 b1 = *(const float4*)&wrow[256 + ln * 4];
      float av[8] = {a0.x, a0.y, a0.z, a0.w, a1.x, a1.y, a1.z, a1.w};
      float bv[8] = {b0.x, b0.y, b0.z, b0.w, b1.x, b1.y, b1.z, b1.w};
#pragma unroll
      for (int i = 0; i < 8; i++)
#pragma unroll
        for (int j = 0; j < 8; j++) acc[i][j] = fmaf(av[i], bv[j], acc[i][j]);
    }
  }

  __syncthreads();  // done with Wxs; reuse as T[512][34] bf16
  char* T = smem + 16384;
  const float* Sb = S + (size_t)b * Nx * Nx;
#pragma unroll
  for (int ii = 0; ii < 8; ii++) {
    const int iloc = w * 8 + ii;
    const float* Srow = Sb + (size_t)(i0 + iloc) * Nx;
    float4 s0 = *(const float4*)&Srow[ln * 4];
    float4 s1 = *(const float4*)&Srow[256 + ln * 4];
    float Sv[8] = {s0.x, s0.y, s0.z, s0.w, s1.x, s1.y, s1.z, s1.w};
    float sc[8];
    int mk[8];
    float rmax = -INF_NUM;
#pragma unroll
    for (int j = 0; j < 8; j++) {
      mk[j] = fabsf(Sv[j]) > ZERO_TOL;
      float v = acc[ii][j];
      float l = v >= 0.f ? v : NEG_SLOPE * v;
      sc[j] = mk[j] ? l : -INF_NUM;
      rmax = fmaxf(rmax, sc[j]);
    }
#pragma unroll
    for (int off = 32; off >= 1; off >>= 1)
      rmax = fmaxf(rmax, __shfl_xor(rmax, off, 64));
    float rsum = 0.f;
#pragma unroll
    for (int j = 0; j < 8; j++) {
      sc[j] = mk[j] ? __expf(sc[j] - rmax) : 0.f;
      rsum += sc[j];
    }
#pragma unroll
    for (int off = 32; off >= 1; off >>= 1) rsum += __shfl_xor(rsum, off, 64);
    float inv = rsum > 0.f ? 1.f / rsum : 0.f;
    // write T[j][iloc], staggered to spread banks
    const int st = ln & 3;
#pragma unroll
    for (int jj0 = 0; jj0 < 4; jj0++) {
      int jj = (jj0 + st) & 3;
      *(u16*)(T + (ln * 4 + jj) * 68 + iloc * 2) = f2b(sc[jj] * inv);
      *(u16*)(T + (256 + ln * 4 + jj) * 68 + iloc * 2) = f2b(sc[4 + jj] * inv);
    }
  }
  __syncthreads();
  // copy-out T -> aijT[j][i0..i0+31], dword-wise coalesced
  u16* dst = aijT + (size_t)bp * Nx * Nx;
  for (int it = 0; it < 32; it++) {
    int idx = tid + it * 256;
    int j = idx >> 4, dw = idx & 15;
    u32 v = *(u32*)(T + j * 68 + dw * 4);
    *(u32*)&dst[(size_t)j * Nx + i0 + dw * 2] = v;
  }
}

// ---------------------------------------------------------------------------
// NT-GEMM core: C[r][c] = sum_k A[r][k]*B[c][k]  (bf16 in, fp32 accum, MFMA)
// BLOCK 64r x 128c, 4 waves (2r x 2c), each wave 32r x 64c = 2x4 frags of 16x16.
// BK=32. LDS: A[64][32] + B[128][32] bf16, XOR(r&3) swizzled via pre-swizzled
// global source with global_load_lds width 16.
// MODE 0: hop1  A=aijT(bp)  B=xb(b)    -> z1[g][m] + z1T[m][g]
// MODE 1: hop2  A=z1(bp)    B=aijT(bp) -> z2T[m][g]
// MODE 2: filt  A={xTb,z1T,z2T} segs  B=Hb(p) -> out[f][n] fp32 (+bias, relu)
// ---------------------------------------------------------------------------
template <int MODE>
__global__ __launch_bounds__(256) void gnt_kernel(const u16* __restrict__ pA,
                                                  const u16* __restrict__ pB,
                                                  const u16* __restrict__ pC,
                                                  const u16* __restrict__ pHb,
                                                  u16* __restrict__ o1,
                                                  u16* __restrict__ o2,
                                                  float* __restrict__ oF,
                                                  const float* __restrict__ bias) {
  __shared__ __align__(16) char smem[4096 + 8192];  // A tile | B tile
  const int bp = blockIdx.x;
  const int b = bp >> 2, p = bp & 3;
  const int by = blockIdx.y;
  const int rt = (MODE == 1) ? (by >> 2) : by;
  const int ct = (MODE == 1) ? (by & 3) : 0;
  const int tid = threadIdx.x;
  const int w = tid >> 6, l = tid & 63;
  const int wr = w >> 1, wc = w & 1;
  const int lr = l & 15, kslot = l >> 4;

  constexpr int KTOT = (MODE == 2) ? (Kx * Gx) : Nx;
  constexpr int SA = (MODE == 2) ? Gx : Nx;
  constexpr int SB = (MODE == 2) ? (Kx * Gx) : Nx;

  const u16* Abase;
  const u16* Bbase;
  if (MODE == 0) {
    Abase = pA + (size_t)bp * Nx * Nx + (size_t)rt * 64 * Nx;
    Bbase = pB + (size_t)b * Gx * Nx;
  } else if (MODE == 1) {
    Abase = pA + (size_t)bp * Gx * Nx + (size_t)rt * 64 * Nx;
    Bbase = pB + (size_t)bp * Nx * Nx + (size_t)ct * 128 * Nx;
  } else {
    Abase = nullptr;  // per-segment below
    Bbase = pHb + (size_t)p * Fx * (Kx * Gx);
  }

  // staging thread->chunk mapping (constant across k-steps)
  const int sar = tid >> 2, sakq = tid & 3;           // A: 256 chunks
  const int sakg = sakq ^ (sar & 3);
  const int sbr0 = tid >> 2, sbkg0 = (tid & 3) ^ (sbr0 & 3);       // B chunk tid
  const int sbr1 = (tid + 256) >> 2, sbkg1 = (tid & 3) ^ (sbr1 & 3);  // B chunk tid+256
  char* ldsAdst = smem + w * 1024;
  char* ldsBdst0 = smem + 4096 + w * 1024;
  char* ldsBdst1 = smem + 4096 + 4096 + w * 1024;

  // fragment LDS byte offsets (constant)
  int aoff[2], boff[4];
#pragma unroll
  for (int fr = 0; fr < 2; fr++) {
    int row = wr * 32 + fr * 16 + lr;
    aoff[fr] = row * 64 + ((kslot ^ (row & 3)) * 16);
  }
#pragma unroll
  for (int fc = 0; fc < 4; fc++) {
    int row = wc * 64 + fc * 16 + lr;
    boff[fc] = 4096 + row * 64 + ((kslot ^ (row & 3)) * 16);
  }

  v4f acc[2][4];
#pragma unroll
  for (int fr = 0; fr < 2; fr++)
#pragma unroll
    for (int fc = 0; fc < 4; fc++) acc[fr][fc] = (v4f){0.f, 0.f, 0.f, 0.f};

  for (int k0 = 0; k0 < KTOT; k0 += 32) {
    const u16* Aseg;
    int kin;
    if (MODE == 2) {
      int seg = k0 >> 7;
      kin = k0 & 127;
      const u16* base = (seg == 0) ? (pA + (size_t)b * Nx * Gx)
                       : (seg == 1) ? (pB + (size_t)bp * Nx * Gx)
                                    : (pC + (size_t)bp * Nx * Gx);
      Aseg = base + (size_t)rt * 64 * Gx;
    } else {
      Aseg = Abase;
      kin = k0;
    }
    __syncthreads();
    G2L16(Aseg + (size_t)sar * SA + kin + sakg * 8, ldsAdst);
    G2L16(Bbase + (size_t)sbr0 * SB + k0 + sbkg0 * 8, ldsBdst0);
    G2L16(Bbase + (size_t)sbr1 * SB + k0 + sbkg1 * 8, ldsBdst1);
    __syncthreads();

    v8bf af[2], bf[4];
#pragma unroll
    for (int fr = 0; fr < 2; fr++) af[fr] = *(const v8bf*)(smem + aoff[fr]);
#pragma unroll
    for (int fc = 0; fc < 4; fc++) bf[fc] = *(const v8bf*)(smem + boff[fc]);
#pragma unroll
    for (int fr = 0; fr < 2; fr++)
#pragma unroll
      for (int fc = 0; fc < 4; fc++)
        acc[fr][fc] = __builtin_amdgcn_mfma_f32_16x16x32_bf16(af[fr], bf[fc],
                                                              acc[fr][fc], 0, 0, 0);
  }

  // epilogue
  if (MODE == 0) {
    u16* z1p = o1 + (size_t)bp * Gx * Nx;   // [g][m]
    u16* z1Tp = o2 + (size_t)bp * Nx * Gx;  // [m][g]
#pragma unroll
    for (int fr = 0; fr < 2; fr++)
#pragma unroll
      for (int fc = 0; fc < 4; fc++) {
        int m0 = rt * 64 + wr * 32 + fr * 16 + kslot * 4;
        int g = wc * 64 + fc * 16 + lr;
        v4f a = acc[fr][fc];
        ushort4 pk;
        pk.x = f2b(a[0]); pk.y = f2b(a[1]); pk.z = f2b(a[2]); pk.w = f2b(a[3]);
        *(ushort4*)&z1p[(size_t)g * Nx + m0] = pk;
        z1Tp[(size_t)(m0 + 0) * Gx + g] = pk.x;
        z1Tp[(size_t)(m0 + 1) * Gx + g] = pk.y;
        z1Tp[(size_t)(m0 + 2) * Gx + g] = pk.z;
        z1Tp[(size_t)(m0 + 3) * Gx + g] = pk.w;
      }
  } else if (MODE == 1) {
    u16* z2Tp = o1 + (size_t)bp * Nx * Gx;  // [m][g]
#pragma unroll
    for (int fr = 0; fr < 2; fr++)
#pragma unroll
      for (int fc = 0; fc < 4; fc++) {
        int g0r = rt * 64 + wr * 32 + fr * 16 + kslot * 4;
        int m = ct * 128 + wc * 64 + fc * 16 + lr;
        v4f a = acc[fr][fc];
        ushort4 pk;
        pk.x = f2b(a[0]); pk.y = f2b(a[1]); pk.z = f2b(a[2]); pk.w = f2b(a[3]);
        *(ushort4*)&z2Tp[(size_t)m * Gx + g0r] = pk;
      }
  } else {
    float* op = oF + (size_t)(b * Px + p) * Fx * Nx;  // [f][n]
#pragma unroll
    for (int fc = 0; fc < 4; fc++) {
      int f = wc * 64 + fc * 16 + lr;
      float bi = bias[f];
#pragma unroll
      for (int fr = 0; fr < 2; fr++) {
        int n0 = rt * 64 + wr * 32 + fr * 16 + kslot * 4;
        v4f a = acc[fr][fc];
        float4 o;
        o.x = fmaxf(a[0] + bi, 0.f);
        o.y = fmaxf(a[1] + bi, 0.f);
        o.z = fmaxf(a[2] + bi, 0.f);
        o.w = fmaxf(a[3] + bi, 0.f);
        *(float4*)&op[(size_t)f * Nx + n0] = o;
      }
    }
  }
}

// ---------------------------------------------------------------------------
extern "C" void kernel_launch(void* const* d_in, const int* in_sizes, int n_in,
                              void* d_out, int out_size, void* d_ws, size_t ws_size,
                              hipStream_t stream) {
  const float* x = (const float*)d_in[0];
  const float* S = (const float*)d_in[1];
  const float* W = (const float*)d_in[2];
  const float* h = (const float*)d_in[4];
  const float* bias = (const float*)d_in[5];
  float* out = (float*)d_out;

  char* ws = (char*)d_ws;
  float* Wx = (float*)(ws);                      // 16 MB
  u16* aijT = (u16*)(ws + (16u << 20));          // 32 MB
  u16* xb = (u16*)(ws + (48u << 20));            // 2 MB
  u16* xTb = (u16*)(ws + (50u << 20));           // 2 MB
  u16* z1 = (u16*)(ws + (52u << 20));            // 8 MB
  u16* z1T = (u16*)(ws + (60u << 20));           // 8 MB
  u16* z2T = (u16*)(ws + (68u << 20));           // 8 MB
  u16* Hb = (u16*)(ws + (76u << 20));            // 384 KB

  castx_kernel<<<dim3(Gx / 32, Nx / 32, Bx), 256, 0, stream>>>(x, xb, xTb);
  casth_kernel<<<dim3(Px * Fx * Kx * Gx / 1024), 256, 0, stream>>>(h, Hb);
  wx_kernel<<<dim3(Bx * Px, Nx / 64), 256, 0, stream>>>(x, W, Wx);
  attn2_kernel<<<dim3(Bx * Px, Nx / 32), 256, 0, stream>>>(x, S, Wx, aijT);
  gnt_kernel<0><<<dim3(Bx * Px, 8), 256, 0, stream>>>(aijT, xb, nullptr, nullptr,
                                                      z1, z1T, nullptr, nullptr);
  gnt_kernel<1><<<dim3(Bx * Px, 8), 256, 0, stream>>>(z1, aijT, nullptr, nullptr,
                                                      z2T, nullptr, nullptr, nullptr);
  gnt_kernel<2><<<dim3(Bx * Px, 8), 256, 0, stream>>>(xTb, z1T, z2T, Hb,
                                                      nullptr, nullptr, out, bias);
  (void)in_sizes; (void)n_in; (void)out_size; (void)ws_size; (void)Wx;
}

// Round 3
// 100.931 us; speedup vs baseline: 4.0633x; 1.5110x over previous
//
#include <hip/hip_runtime.h>

#define Bx 16
#define Gx 128
#define Nx 512
#define Px 4
#define Kx 3
#define Fx 128
#define NEG_SLOPE 0.2f
#define ZERO_TOL 1e-9f
#define BIGF 1.0e30f

typedef unsigned short u16;
typedef unsigned int u32;
typedef __bf16 v8bf __attribute__((ext_vector_type(8)));
typedef float v4f __attribute__((ext_vector_type(4)));

__device__ __forceinline__ u16 f2b(float f) {
  union { float f; u32 u; } v; v.f = f;
  u32 r = (v.u + 0x7fffu + ((v.u >> 16) & 1u)) >> 16;
  return (u16)r;
}
__device__ __forceinline__ float b2f(u16 h) {
  union { u32 u; float f; } v; v.u = ((u32)h) << 16;
  return v.f;
}

// async global->LDS, 16B per lane; LDS dst must be wave-uniform base (+lane*16)
#define G2L16(gsrc, ldst)                                                     \
  __builtin_amdgcn_global_load_lds(                                           \
      (const __attribute__((address_space(1))) void*)(gsrc),                  \
      (__attribute__((address_space(3))) void*)(ldst), 16, 0, 0)

// ---------------------------------------------------------------------------
// mask: bit j of word mb[(b*N+i)*16 + j/32] = |S[b,0,i,j]| > tol
// ---------------------------------------------------------------------------
__global__ __launch_bounds__(256) void mask_kernel(const float* __restrict__ S,
                                                   u32* __restrict__ mb) {
  const int wi = blockIdx.x * 256 + threadIdx.x;  // word index
  const float4* S4 = (const float4*)S;
  u32 bits = 0;
#pragma unroll
  for (int q = 0; q < 8; q++) {
    float4 v = S4[(size_t)wi * 8 + q];
    bits |= (fabsf(v.x) > ZERO_TOL ? 1u : 0u) << (q * 4);
    bits |= (fabsf(v.y) > ZERO_TOL ? 2u : 0u) << (q * 4);
    bits |= (fabsf(v.z) > ZERO_TOL ? 4u : 0u) << (q * 4);
    bits |= (fabsf(v.w) > ZERO_TOL ? 8u : 0u) << (q * 4);
  }
  mb[wi] = bits;
}

// ---------------------------------------------------------------------------
// castx2: x -> xb (bf16 [b][g][n]) and xT hi/lo ([b][n][g])
// ---------------------------------------------------------------------------
__global__ __launch_bounds__(256) void castx2_kernel(const float* __restrict__ x,
                                                     u16* __restrict__ xb,
                                                     u16* __restrict__ xth,
                                                     u16* __restrict__ xtl) {
  const int b = blockIdx.z, g0 = blockIdx.x * 32, n0 = blockIdx.y * 32;
  const int tid = threadIdx.x;
  __shared__ float t[32][33];
  const int r = tid >> 3, c4 = (tid & 7) * 4;
  const float* xp = x + (size_t)b * Gx * Nx;
  float4 v = *(const float4*)&xp[(g0 + r) * Nx + n0 + c4];
  ushort4 o;
  o.x = f2b(v.x); o.y = f2b(v.y); o.z = f2b(v.z); o.w = f2b(v.w);
  *(ushort4*)&xb[(size_t)b * Gx * Nx + (g0 + r) * Nx + n0 + c4] = o;
  t[r][c4 + 0] = v.x; t[r][c4 + 1] = v.y; t[r][c4 + 2] = v.z; t[r][c4 + 3] = v.w;
  __syncthreads();
  float tv[4] = {t[c4 + 0][r], t[c4 + 1][r], t[c4 + 2][r], t[c4 + 3][r]};
  ushort4 hh, ll;
  u16 h0 = f2b(tv[0]); ll.x = f2b(tv[0] - b2f(h0)); hh.x = h0;
  u16 h1 = f2b(tv[1]); ll.y = f2b(tv[1] - b2f(h1)); hh.y = h1;
  u16 h2 = f2b(tv[2]); ll.z = f2b(tv[2] - b2f(h2)); hh.z = h2;
  u16 h3 = f2b(tv[3]); ll.w = f2b(tv[3] - b2f(h3)); hh.w = h3;
  size_t off = (size_t)b * Nx * Gx + (size_t)(n0 + r) * Gx + g0 + c4;
  *(ushort4*)&xth[off] = hh;
  *(ushort4*)&xtl[off] = ll;
}

// castw: W (P,G,G) -> hi/lo bf16
__global__ __launch_bounds__(256) void castw_kernel(const float* __restrict__ W,
                                                    u16* __restrict__ wh,
                                                    u16* __restrict__ wl) {
  int i4 = (blockIdx.x * 256 + threadIdx.x) * 4;
  float4 v = *(const float4*)&W[i4];
  ushort4 hh, ll;
  hh.x = f2b(v.x); ll.x = f2b(v.x - b2f(hh.x));
  hh.y = f2b(v.y); ll.y = f2b(v.y - b2f(hh.y));
  hh.z = f2b(v.z); ll.z = f2b(v.z - b2f(hh.z));
  hh.w = f2b(v.w); ll.w = f2b(v.w - b2f(hh.w));
  *(ushort4*)&wh[i4] = hh;
  *(ushort4*)&wl[i4] = ll;
}

// casth: h flat -> bf16
__global__ __launch_bounds__(256) void casth_kernel(const float* __restrict__ h,
                                                    u16* __restrict__ Hb) {
  int i4 = (blockIdx.x * 256 + threadIdx.x) * 4;
  float4 v = *(const float4*)&h[i4];
  ushort4 o;
  o.x = f2b(v.x); o.y = f2b(v.y); o.z = f2b(v.z); o.w = f2b(v.w);
  *(ushort4*)&Hb[i4] = o;
}

// ---------------------------------------------------------------------------
// wxt: WxT[n][g] = sum_h xT[n][h] * W[g][h]  (split-bf16 MFMA, fp32 acc)
// emits WxT hi/lo. grid (B*P, N/64), 256 thr, block 64n x 128g, K=128.
// ---------------------------------------------------------------------------
__global__ __launch_bounds__(256) void wxt_kernel(const u16* __restrict__ xth,
                                                  const u16* __restrict__ xtl,
                                                  const u16* __restrict__ wh,
                                                  const u16* __restrict__ wl,
                                                  u16* __restrict__ oh,
                                                  u16* __restrict__ ol) {
  __shared__ __align__(16) char smem[24576];
  const int bp = blockIdx.x, b = bp >> 2, p = bp & 3;
  const int rt = blockIdx.y;
  const int tid = threadIdx.x;
  const int w = tid >> 6, l = tid & 63;
  const int wr = w >> 1, wc = w & 1;
  const int lr = l & 15, ks = l >> 4;

  const u16* Ah = xth + ((size_t)b * Nx + rt * 64) * Gx;
  const u16* Al = xtl + ((size_t)b * Nx + rt * 64) * Gx;
  const u16* Bh = wh + (size_t)p * Gx * Gx;
  const u16* Bl = wl + (size_t)p * Gx * Gx;

  const int sr = tid >> 2, kq = tid & 3;
  const int kg = (kq ^ (sr & 3)) * 8;
  const int sr1 = sr + 64;
  const int kg1 = (kq ^ (sr1 & 3)) * 8;

  v4f acc[2][4];
#pragma unroll
  for (int fr = 0; fr < 2; fr++)
#pragma unroll
    for (int fc = 0; fc < 4; fc++) acc[fr][fc] = (v4f){0.f, 0.f, 0.f, 0.f};

  for (int k0 = 0; k0 < Gx; k0 += 32) {
    __syncthreads();
    char* dA = smem + w * 1024;
    char* dB = smem + 8192 + w * 1024;
    G2L16(Ah + (size_t)sr * Gx + k0 + kg, dA);
    G2L16(Al + (size_t)sr * Gx + k0 + kg, dA + 4096);
    G2L16(Bh + (size_t)sr * Gx + k0 + kg, dB);
    G2L16(Bh + (size_t)sr1 * Gx + k0 + kg1, dB + 4096);
    G2L16(Bl + (size_t)sr * Gx + k0 + kg, dB + 8192);
    G2L16(Bl + (size_t)sr1 * Gx + k0 + kg1, dB + 8192 + 4096);
    __syncthreads();

    v8bf ah[2], al2[2];
#pragma unroll
    for (int fr = 0; fr < 2; fr++) {
      int ra = wr * 32 + fr * 16 + lr;
      int off = ra * 64 + ((ks ^ (ra & 3)) * 16);
      ah[fr] = *(const v8bf*)(smem + off);
      al2[fr] = *(const v8bf*)(smem + 4096 + off);
    }
#pragma unroll
    for (int fc = 0; fc < 4; fc++) {
      int rb = wc * 64 + fc * 16 + lr;
      int boff = 8192 + rb * 64 + ((ks ^ (rb & 3)) * 16);
      v8bf bh = *(const v8bf*)(smem + boff);
      v8bf bl = *(const v8bf*)(smem + boff + 8192);
#pragma unroll
      for (int fr = 0; fr < 2; fr++) {
        acc[fr][fc] = __builtin_amdgcn_mfma_f32_16x16x32_bf16(al2[fr], bh, acc[fr][fc], 0, 0, 0);
        acc[fr][fc] = __builtin_amdgcn_mfma_f32_16x16x32_bf16(ah[fr], bl, acc[fr][fc], 0, 0, 0);
        acc[fr][fc] = __builtin_amdgcn_mfma_f32_16x16x32_bf16(ah[fr], bh, acc[fr][fc], 0, 0, 0);
      }
    }
  }

  u16* ohp = oh + (size_t)bp * Nx * Gx;
  u16* olp = ol + (size_t)bp * Nx * Gx;
#pragma unroll
  for (int fr = 0; fr < 2; fr++)
#pragma unroll
    for (int fc = 0; fc < 4; fc++) {
      int n = rt * 64 + wr * 32 + fr * 16 + ks * 4;
      int g = wc * 64 + fc * 16 + lr;
#pragma unroll
      for (int q = 0; q < 4; q++) {
        float a = acc[fr][fc][q];
        u16 hi = f2b(a);
        u16 lo = f2b(a - b2f(hi));
        ohp[(size_t)(n + q) * Gx + g] = hi;
        olp[(size_t)(n + q) * Gx + g] = lo;
      }
    }
}

// ---------------------------------------------------------------------------
// attn3: scores[i][j] = sum_g xT[i][g]*WxT[j][g] (split-bf16 MFMA);
// leaky, mask (bitmap), softmax over j, write aijT[j][i] bf16.
// grid (B*P, N/64), 512 thr (8 waves = 2i x 4j). Block: 64 i x 512 j, K=128.
// ---------------------------------------------------------------------------
__global__ __launch_bounds__(512) void attn3_kernel(const u16* __restrict__ xth,
                                                    const u16* __restrict__ xtl,
                                                    const u16* __restrict__ WxTh,
                                                    const u16* __restrict__ WxTl,
                                                    const u32* __restrict__ mb,
                                                    u16* __restrict__ aijT) {
  __shared__ __align__(16) char smem[104448];
  constexpr int OA_LO = 16384, OB_HI = 32768, OB_LO = 65536;
  constexpr int OMBS = 98304, ORED = 102400;
  const int bp = blockIdx.x, b = bp >> 2;
  const int i0 = blockIdx.y * 64;
  const int tid = threadIdx.x;
  const int w = tid >> 6, l = tid & 63;
  const int wr = w >> 2, wc = w & 3;
  const int lr = l & 15, ks = l >> 4;

  {  // mask rows -> LDS (64 rows x 16 words)
    const u32* mbp = mb + ((size_t)b * Nx + i0) * 16;
    u32* mbs = (u32*)(smem + OMBS);
    mbs[tid] = mbp[tid];
    mbs[tid + 512] = mbp[tid + 512];
  }
  {  // stage A: xT hi/lo rows i0..i0+63, K=128 (chunk-XOR swizzled by row&15)
    const u16* Ah = xth + ((size_t)b * Nx + i0) * Gx;
    const u16* Al = xtl + ((size_t)b * Nx + i0) * Gx;
    const int sr = tid >> 4, kq = tid & 15;
    const int kg = (kq ^ (sr & 15)) * 8;
    char* dA = smem + w * 1024;
    G2L16(Ah + (size_t)sr * Gx + kg, dA);
    G2L16(Ah + (size_t)(sr + 32) * Gx + kg, dA + 8192);
    G2L16(Al + (size_t)sr * Gx + kg, dA + OA_LO);
    G2L16(Al + (size_t)(sr + 32) * Gx + kg, dA + OA_LO + 8192);
  }

  v4f acc[2][8];
#pragma unroll
  for (int fr = 0; fr < 2; fr++)
#pragma unroll
    for (int fc = 0; fc < 8; fc++) acc[fr][fc] = (v4f){0.f, 0.f, 0.f, 0.f};

  const u16* Bh = WxTh + (size_t)bp * Nx * Gx;
  const u16* Bl = WxTl + (size_t)bp * Nx * Gx;
  const int sbr = tid >> 2, sbq = tid & 3;
  const int sbkg = (sbq ^ (sbr & 3)) * 8;

  for (int g0 = 0; g0 < Gx; g0 += 32) {
    __syncthreads();
    char* dB = smem + OB_HI + w * 1024;
#pragma unroll
    for (int is = 0; is < 4; is++) {
      const size_t ro = (size_t)(sbr + is * 128) * Gx + g0 + sbkg;
      G2L16(Bh + ro, dB + is * 8192);
      G2L16(Bl + ro, dB + (OB_LO - OB_HI) + is * 8192);
    }
    __syncthreads();

    v8bf ah[2], al2[2];
#pragma unroll
    for (int fr = 0; fr < 2; fr++) {
      int ra = wr * 32 + fr * 16 + lr;
      int kk = (g0 >> 3) + ks;
      int off = ra * 256 + ((kk ^ (ra & 15)) * 16);
      ah[fr] = *(const v8bf*)(smem + off);
      al2[fr] = *(const v8bf*)(smem + OA_LO + off);
    }
#pragma unroll
    for (int fc = 0; fc < 8; fc++) {
      int rb = wc * 128 + fc * 16 + lr;
      int boff = OB_HI + rb * 64 + ((ks ^ (rb & 3)) * 16);
      v8bf bh = *(const v8bf*)(smem + boff);
      v8bf bl = *(const v8bf*)(smem + boff + (OB_LO - OB_HI));
#pragma unroll
      for (int fr = 0; fr < 2; fr++) {
        acc[fr][fc] = __builtin_amdgcn_mfma_f32_16x16x32_bf16(al2[fr], bh, acc[fr][fc], 0, 0, 0);
        acc[fr][fc] = __builtin_amdgcn_mfma_f32_16x16x32_bf16(ah[fr], bl, acc[fr][fc], 0, 0, 0);
        acc[fr][fc] = __builtin_amdgcn_mfma_f32_16x16x32_bf16(ah[fr], bh, acc[fr][fc], 0, 0, 0);
      }
    }
  }

  u32* mbs = (u32*)(smem + OMBS);
  float* red0 = (float*)(smem + ORED);
  float* red1 = red0 + 256;

  // pass 1: masked leaky-relu + wave-local row max
#pragma unroll
  for (int fr = 0; fr < 2; fr++)
#pragma unroll
    for (int q = 0; q < 4; q++) {
      int row = wr * 32 + fr * 16 + ks * 4 + q;
      float m = -BIGF;
#pragma unroll
      for (int fc = 0; fc < 8; fc++) {
        u32 word = mbs[row * 16 + wc * 4 + (fc >> 1)];
        int bit = ((fc & 1) << 4) + lr;
        float v = acc[fr][fc][q];
        v = v >= 0.f ? v : NEG_SLOPE * v;
        v = ((word >> bit) & 1u) ? v : -BIGF;
        acc[fr][fc][q] = v;
        m = fmaxf(m, v);
      }
      m = fmaxf(m, __shfl_xor(m, 1, 64));
      m = fmaxf(m, __shfl_xor(m, 2, 64));
      m = fmaxf(m, __shfl_xor(m, 4, 64));
      m = fmaxf(m, __shfl_xor(m, 8, 64));
      if (lr == 0) red0[row * 4 + wc] = m;
    }
  __syncthreads();
  // pass 2: global max, exp, wave-local sum
#pragma unroll
  for (int fr = 0; fr < 2; fr++)
#pragma unroll
    for (int q = 0; q < 4; q++) {
      int row = wr * 32 + fr * 16 + ks * 4 + q;
      float4 pm = *(const float4*)&red0[row * 4];
      float gm = fmaxf(fmaxf(pm.x, pm.y), fmaxf(pm.z, pm.w));
      float s = 0.f;
#pragma unroll
      for (int fc = 0; fc < 8; fc++) {
        float v = acc[fr][fc][q];
        float e = (v <= -0.5f * BIGF) ? 0.f : __expf(v - gm);
        acc[fr][fc][q] = e;
        s += e;
      }
      s += __shfl_xor(s, 1, 64);
      s += __shfl_xor(s, 2, 64);
      s += __shfl_xor(s, 4, 64);
      s += __shfl_xor(s, 8, 64);
      if (lr == 0) red1[row * 4 + wc] = s;
    }
  __syncthreads();
  // pass 3: normalize, bf16, transpose via LDS T[512][66]
  char* T = smem;  // reuses A+B regions (all MFMA reads done)
#pragma unroll
  for (int fr = 0; fr < 2; fr++)
#pragma unroll
    for (int q = 0; q < 4; q++) {
      int row = wr * 32 + fr * 16 + ks * 4 + q;
      float4 ps = *(const float4*)&red1[row * 4];
      float tot = (ps.x + ps.y) + (ps.z + ps.w);
      float inv = tot > 0.f ? 1.f / tot : 0.f;
#pragma unroll
      for (int fc = 0; fc < 8; fc++) {
        int j = wc * 128 + fc * 16 + lr;
        *(u16*)(T + (size_t)j * 132 + row * 2) = f2b(acc[fr][fc][q] * inv);
      }
    }
  __syncthreads();
  // copy-out: T -> aijT[j][i0..i0+63], u32-coalesced
  u16* dst = aijT + (size_t)bp * Nx * Nx + i0;
#pragma unroll 4
  for (int it = 0; it < 32; it++) {
    int idx = it * 512 + tid;
    int j = idx >> 5, c = idx & 31;
    u32 v = *(const u32*)(T + (size_t)j * 132 + c * 4);
    *(u32*)&dst[(size_t)j * Nx + c * 2] = v;
  }
}

// ---------------------------------------------------------------------------
// NT-GEMM core (unchanged from round 2): C[r][c] = sum_k A[r][k]*B[c][k]
// MODE 0: hop1  A=aijT(bp)  B=xb(b)    -> z1[g][m] + z1T[m][g]
// MODE 1: hop2  A=z1(bp)    B=aijT(bp) -> z2T[m][g]
// MODE 2: filt  A={xTh,z1T,z2T} segs  B=Hb(p) -> out[f][n] fp32 (+bias, relu)
// ---------------------------------------------------------------------------
template <int MODE>
__global__ __launch_bounds__(256) void gnt_kernel(const u16* __restrict__ pA,
                                                  const u16* __restrict__ pB,
                                                  const u16* __restrict__ pC,
                                                  const u16* __restrict__ pHb,
                                                  u16* __restrict__ o1,
                                                  u16* __restrict__ o2,
                                                  float* __restrict__ oF,
                                                  const float* __restrict__ bias) {
  __shared__ __align__(16) char smem[4096 + 8192];
  const int bp = blockIdx.x;
  const int b = bp >> 2, p = bp & 3;
  const int by = blockIdx.y;
  const int rt = (MODE == 1) ? (by >> 2) : by;
  const int ct = (MODE == 1) ? (by & 3) : 0;
  const int tid = threadIdx.x;
  const int w = tid >> 6, l = tid & 63;
  const int wr = w >> 1, wc = w & 1;
  const int lr = l & 15, kslot = l >> 4;

  constexpr int KTOT = (MODE == 2) ? (Kx * Gx) : Nx;
  constexpr int SA = (MODE == 2) ? Gx : Nx;
  constexpr int SB = (MODE == 2) ? (Kx * Gx) : Nx;

  const u16* Abase;
  const u16* Bbase;
  if (MODE == 0) {
    Abase = pA + (size_t)bp * Nx * Nx + (size_t)rt * 64 * Nx;
    Bbase = pB + (size_t)b * Gx * Nx;
  } else if (MODE == 1) {
    Abase = pA + (size_t)bp * Gx * Nx + (size_t)rt * 64 * Nx;
    Bbase = pB + (size_t)bp * Nx * Nx + (size_t)ct * 128 * Nx;
  } else {
    Abase = nullptr;
    Bbase = pHb + (size_t)p * Fx * (Kx * Gx);
  }

  const int sar = tid >> 2, sakq = tid & 3;
  const int sakg = sakq ^ (sar & 3);
  const int sbr0 = tid >> 2, sbkg0 = (tid & 3) ^ (sbr0 & 3);
  const int sbr1 = (tid + 256) >> 2, sbkg1 = (tid & 3) ^ (sbr1 & 3);
  char* ldsAdst = smem + w * 1024;
  char* ldsBdst0 = smem + 4096 + w * 1024;
  char* ldsBdst1 = smem + 4096 + 4096 + w * 1024;

  int aoff[2], boff[4];
#pragma unroll
  for (int fr = 0; fr < 2; fr++) {
    int row = wr * 32 + fr * 16 + lr;
    aoff[fr] = row * 64 + ((kslot ^ (row & 3)) * 16);
  }
#pragma unroll
  for (int fc = 0; fc < 4; fc++) {
    int row = wc * 64 + fc * 16 + lr;
    boff[fc] = 4096 + row * 64 + ((kslot ^ (row & 3)) * 16);
  }

  v4f acc[2][4];
#pragma unroll
  for (int fr = 0; fr < 2; fr++)
#pragma unroll
    for (int fc = 0; fc < 4; fc++) acc[fr][fc] = (v4f){0.f, 0.f, 0.f, 0.f};

  for (int k0 = 0; k0 < KTOT; k0 += 32) {
    const u16* Aseg;
    int kin;
    if (MODE == 2) {
      int seg = k0 >> 7;
      kin = k0 & 127;
      const u16* base = (seg == 0) ? (pA + (size_t)b * Nx * Gx)
                       : (seg == 1) ? (pB + (size_t)bp * Nx * Gx)
                                    : (pC + (size_t)bp * Nx * Gx);
      Aseg = base + (size_t)rt * 64 * Gx;
    } else {
      Aseg = Abase;
      kin = k0;
    }
    __syncthreads();
    G2L16(Aseg + (size_t)sar * SA + kin + sakg * 8, ldsAdst);
    G2L16(Bbase + (size_t)sbr0 * SB + k0 + sbkg0 * 8, ldsBdst0);
    G2L16(Bbase + (size_t)sbr1 * SB + k0 + sbkg1 * 8, ldsBdst1);
    __syncthreads();

    v8bf af[2], bf[4];
#pragma unroll
    for (int fr = 0; fr < 2; fr++) af[fr] = *(const v8bf*)(smem + aoff[fr]);
#pragma unroll
    for (int fc = 0; fc < 4; fc++) bf[fc] = *(const v8bf*)(smem + boff[fc]);
#pragma unroll
    for (int fr = 0; fr < 2; fr++)
#pragma unroll
      for (int fc = 0; fc < 4; fc++)
        acc[fr][fc] = __builtin_amdgcn_mfma_f32_16x16x32_bf16(af[fr], bf[fc],
                                                              acc[fr][fc], 0, 0, 0);
  }

  if (MODE == 0) {
    u16* z1p = o1 + (size_t)bp * Gx * Nx;
    u16* z1Tp = o2 + (size_t)bp * Nx * Gx;
#pragma unroll
    for (int fr = 0; fr < 2; fr++)
#pragma unroll
      for (int fc = 0; fc < 4; fc++) {
        int m0 = rt * 64 + wr * 32 + fr * 16 + kslot * 4;
        int g = wc * 64 + fc * 16 + lr;
        v4f a = acc[fr][fc];
        ushort4 pk;
        pk.x = f2b(a[0]); pk.y = f2b(a[1]); pk.z = f2b(a[2]); pk.w = f2b(a[3]);
        *(ushort4*)&z1p[(size_t)g * Nx + m0] = pk;
        z1Tp[(size_t)(m0 + 0) * Gx + g] = pk.x;
        z1Tp[(size_t)(m0 + 1) * Gx + g] = pk.y;
        z1Tp[(size_t)(m0 + 2) * Gx + g] = pk.z;
        z1Tp[(size_t)(m0 + 3) * Gx + g] = pk.w;
      }
  } else if (MODE == 1) {
    u16* z2Tp = o1 + (size_t)bp * Nx * Gx;
#pragma unroll
    for (int fr = 0; fr < 2; fr++)
#pragma unroll
      for (int fc = 0; fc < 4; fc++) {
        int g0r = rt * 64 + wr * 32 + fr * 16 + kslot * 4;
        int m = ct * 128 + wc * 64 + fc * 16 + lr;
        v4f a = acc[fr][fc];
        ushort4 pk;
        pk.x = f2b(a[0]); pk.y = f2b(a[1]); pk.z = f2b(a[2]); pk.w = f2b(a[3]);
        *(ushort4*)&z2Tp[(size_t)m * Gx + g0r] = pk;
      }
  } else {
    float* op = oF + (size_t)(b * Px + p) * Fx * Nx;
#pragma unroll
    for (int fc = 0; fc < 4; fc++) {
      int f = wc * 64 + fc * 16 + lr;
      float bi = bias[f];
#pragma unroll
      for (int fr = 0; fr < 2; fr++) {
        int n0 = rt * 64 + wr * 32 + fr * 16 + kslot * 4;
        v4f a = acc[fr][fc];
        float4 o;
        o.x = fmaxf(a[0] + bi, 0.f);
        o.y = fmaxf(a[1] + bi, 0.f);
        o.z = fmaxf(a[2] + bi, 0.f);
        o.w = fmaxf(a[3] + bi, 0.f);
        *(float4*)&op[(size_t)f * Nx + n0] = o;
      }
    }
  }
}

// ---------------------------------------------------------------------------
extern "C" void kernel_launch(void* const* d_in, const int* in_sizes, int n_in,
                              void* d_out, int out_size, void* d_ws, size_t ws_size,
                              hipStream_t stream) {
  const float* x = (const float*)d_in[0];
  const float* S = (const float*)d_in[1];
  const float* W = (const float*)d_in[2];
  const float* h = (const float*)d_in[4];
  const float* bias = (const float*)d_in[5];
  float* out = (float*)d_out;

  char* ws = (char*)d_ws;
  u16* aijT = (u16*)ws;                       // 33,554,432
  u16* WxTh = (u16*)(ws + 33554432);          //  8,388,608
  u16* WxTl = (u16*)(ws + 41943040);          //  8,388,608
  u16* xTh  = (u16*)(ws + 50331648);          //  2,097,152
  u16* xTl  = (u16*)(ws + 52428800);          //  2,097,152
  u16* xb   = (u16*)(ws + 54525952);          //  2,097,152
  u16* z1   = (u16*)(ws + 56623104);          //  8,388,608
  u16* z1T  = (u16*)(ws + 65011712);          //  8,388,608
  u16* z2T  = (u16*)(ws + 73400320);          //  8,388,608
  u16* Hb   = (u16*)(ws + 81788928);          //    393,216
  u16* Wh   = (u16*)(ws + 82182144);          //    131,072
  u16* Wl   = (u16*)(ws + 82313216);          //    131,072
  u32* mb   = (u32*)(ws + 82444288);          //    524,288

  mask_kernel<<<dim3((Bx * Nx * Nx / 32) / 256), 256, 0, stream>>>(S, mb);
  castx2_kernel<<<dim3(Gx / 32, Nx / 32, Bx), 256, 0, stream>>>(x, xb, xTh, xTl);
  castw_kernel<<<dim3(Px * Gx * Gx / 1024), 256, 0, stream>>>(W, Wh, Wl);
  casth_kernel<<<dim3(Px * Fx * Kx * Gx / 1024), 256, 0, stream>>>(h, Hb);
  wxt_kernel<<<dim3(Bx * Px, Nx / 64), 256, 0, stream>>>(xTh, xTl, Wh, Wl, WxTh, WxTl);
  attn3_kernel<<<dim3(Bx * Px, Nx / 64), 512, 0, stream>>>(xTh, xTl, WxTh, WxTl, mb, aijT);
  gnt_kernel<0><<<dim3(Bx * Px, 8), 256, 0, stream>>>(aijT, xb, nullptr, nullptr,
                                                      z1, z1T, nullptr, nullptr);
  gnt_kernel<1><<<dim3(Bx * Px, 8), 256, 0, stream>>>(z1, aijT, nullptr, nullptr,
                                                      z2T, nullptr, nullptr, nullptr);
  gnt_kernel<2><<<dim3(Bx * Px, 8), 256, 0, stream>>>(xTh, z1T, z2T, Hb,
                                                      nullptr, nullptr, out, bias);
  (void)in_sizes; (void)n_in; (void)out_size; (void)ws_size;
}

// Round 6
// 81.243 us; speedup vs baseline: 5.0480x; 1.2423x over previous
//
#include <hip/hip_runtime.h>

#define Bx 16
#define Gx 128
#define Nx 512
#define Px 4
#define Kx 3
#define Fx 128
#define NEG_SLOPE 0.2f
#define ZERO_TOL 1e-9f
#define BIGF 1.0e30f

typedef unsigned short u16;
typedef unsigned int u32;
typedef __bf16 v8bf __attribute__((ext_vector_type(8)));
typedef _Float16 v8hf __attribute__((ext_vector_type(8)));
typedef float v4f __attribute__((ext_vector_type(4)));

__device__ __forceinline__ u16 f2b(float f) {
  union { float f; u32 u; } v; v.f = f;
  u32 r = (v.u + 0x7fffu + ((v.u >> 16) & 1u)) >> 16;
  return (u16)r;
}
__device__ __forceinline__ u16 f2h(float f) {
  union { _Float16 h; u16 u; } v; v.h = (_Float16)f;
  return v.u;
}

// async global->LDS, 16B per lane; LDS dst must be wave-uniform base (+lane*16)
#define G2L16(gsrc, ldst)                                                     \
  __builtin_amdgcn_global_load_lds(                                           \
      (const __attribute__((address_space(1))) void*)(gsrc),                  \
      (__attribute__((address_space(3))) void*)(ldst), 16, 0, 0)

// ---------------------------------------------------------------------------
// mask: bit j of word mb[(b*N+i)*16 + j/32] = |S[b,0,i,j]| > tol
// ---------------------------------------------------------------------------
__global__ __launch_bounds__(256) void mask_kernel(const float* __restrict__ S,
                                                   u32* __restrict__ mb) {
  const int wi = blockIdx.x * 256 + threadIdx.x;
  const float4* S4 = (const float4*)S;
  u32 bits = 0;
#pragma unroll
  for (int q = 0; q < 8; q++) {
    float4 v = S4[(size_t)wi * 8 + q];
    bits |= (fabsf(v.x) > ZERO_TOL ? 1u : 0u) << (q * 4);
    bits |= (fabsf(v.y) > ZERO_TOL ? 2u : 0u) << (q * 4);
    bits |= (fabsf(v.z) > ZERO_TOL ? 4u : 0u) << (q * 4);
    bits |= (fabsf(v.w) > ZERO_TOL ? 8u : 0u) << (q * 4);
  }
  mb[wi] = bits;
}

// ---------------------------------------------------------------------------
// castx3: x -> xb (bf16 [b][g][n]), xTb (bf16 [b][n][g]), xT16 (fp16 [b][n][g])
// ---------------------------------------------------------------------------
__global__ __launch_bounds__(256) void castx3_kernel(const float* __restrict__ x,
                                                     u16* __restrict__ xb,
                                                     u16* __restrict__ xTb,
                                                     u16* __restrict__ xT16) {
  const int b = blockIdx.z, g0 = blockIdx.x * 32, n0 = blockIdx.y * 32;
  const int tid = threadIdx.x;
  __shared__ float t[32][33];
  const int r = tid >> 3, c4 = (tid & 7) * 4;
  const float* xp = x + (size_t)b * Gx * Nx;
  float4 v = *(const float4*)&xp[(g0 + r) * Nx + n0 + c4];
  ushort4 o;
  o.x = f2b(v.x); o.y = f2b(v.y); o.z = f2b(v.z); o.w = f2b(v.w);
  *(ushort4*)&xb[(size_t)b * Gx * Nx + (g0 + r) * Nx + n0 + c4] = o;
  t[r][c4 + 0] = v.x; t[r][c4 + 1] = v.y; t[r][c4 + 2] = v.z; t[r][c4 + 3] = v.w;
  __syncthreads();
  float tv[4] = {t[c4 + 0][r], t[c4 + 1][r], t[c4 + 2][r], t[c4 + 3][r]};
  ushort4 ob, oh;
  ob.x = f2b(tv[0]); oh.x = f2h(tv[0]);
  ob.y = f2b(tv[1]); oh.y = f2h(tv[1]);
  ob.z = f2b(tv[2]); oh.z = f2h(tv[2]);
  ob.w = f2b(tv[3]); oh.w = f2h(tv[3]);
  size_t off = (size_t)b * Nx * Gx + (size_t)(n0 + r) * Gx + g0 + c4;
  *(ushort4*)&xTb[off] = ob;
  *(ushort4*)&xT16[off] = oh;
}

// castw16: W (P,G,G) -> fp16
__global__ __launch_bounds__(256) void castw16_kernel(const float* __restrict__ W,
                                                      u16* __restrict__ w16) {
  int i4 = (blockIdx.x * 256 + threadIdx.x) * 4;
  float4 v = *(const float4*)&W[i4];
  ushort4 o;
  o.x = f2h(v.x); o.y = f2h(v.y); o.z = f2h(v.z); o.w = f2h(v.w);
  *(ushort4*)&w16[i4] = o;
}

// casth: h flat -> bf16
__global__ __launch_bounds__(256) void casth_kernel(const float* __restrict__ h,
                                                    u16* __restrict__ Hb) {
  int i4 = (blockIdx.x * 256 + threadIdx.x) * 4;
  float4 v = *(const float4*)&h[i4];
  ushort4 o;
  o.x = f2b(v.x); o.y = f2b(v.y); o.z = f2b(v.z); o.w = f2b(v.w);
  *(ushort4*)&Hb[i4] = o;
}

// ---------------------------------------------------------------------------
// wxt16: WxT[n][g] = sum_h xT[n][h] * W[g][h]  (fp16 MFMA, fp32 acc, fp16 out)
// grid (B*P, N/64), 256 thr (2x2 waves), block 64n x 128g, K=128 single-stage.
// ---------------------------------------------------------------------------
__global__ __launch_bounds__(256) void wxt16_kernel(const u16* __restrict__ xT16,
                                                    const u16* __restrict__ w16,
                                                    u16* __restrict__ WxT16) {
  __shared__ __align__(16) char smem[49152];
  constexpr int OB = 16384;
  const int bp = blockIdx.x, b = bp >> 2, p = bp & 3;
  const int rt = blockIdx.y;
  const int tid = threadIdx.x;
  const int w = tid >> 6, l = tid & 63;
  const int wr = w >> 1, wc = w & 1;
  const int lr = l & 15, ks = l >> 4;

  const u16* Ap = xT16 + ((size_t)b * Nx + rt * 64) * Gx;
  const u16* Bp = w16 + (size_t)p * Gx * Gx;
#pragma unroll
  for (int it = 0; it < 4; it++) {
    int chunk = it * 256 + w * 64 + l;
    int r = chunk >> 4, kq = l & 15;
    int kg = (kq ^ (r & 15)) * 8;
    G2L16(Ap + (size_t)r * Gx + kg, smem + it * 4096 + w * 1024);
  }
#pragma unroll
  for (int it = 0; it < 8; it++) {
    int chunk = it * 256 + w * 64 + l;
    int r = chunk >> 4, kq = l & 15;
    int kg = (kq ^ (r & 15)) * 8;
    G2L16(Bp + (size_t)r * Gx + kg, smem + OB + it * 4096 + w * 1024);
  }
  __syncthreads();

  v4f acc[2][4];
#pragma unroll
  for (int fr = 0; fr < 2; fr++)
#pragma unroll
    for (int fc = 0; fc < 4; fc++) acc[fr][fc] = (v4f){0.f, 0.f, 0.f, 0.f};

#pragma unroll
  for (int t = 0; t < 4; t++) {
    int kk = t * 4 + ks;
    v8hf ah[2];
#pragma unroll
    for (int fr = 0; fr < 2; fr++) {
      int ra = wr * 32 + fr * 16 + lr;
      ah[fr] = *(const v8hf*)(smem + ra * 256 + ((kk ^ (ra & 15)) * 16));
    }
#pragma unroll
    for (int fc = 0; fc < 4; fc++) {
      int rb = wc * 64 + fc * 16 + lr;
      v8hf bh = *(const v8hf*)(smem + OB + rb * 256 + ((kk ^ (rb & 15)) * 16));
#pragma unroll
      for (int fr = 0; fr < 2; fr++)
        acc[fr][fc] = __builtin_amdgcn_mfma_f32_16x16x32_f16(ah[fr], bh, acc[fr][fc], 0, 0, 0);
    }
  }

  u16* op = WxT16 + (size_t)bp * Nx * Gx;
#pragma unroll
  for (int fr = 0; fr < 2; fr++)
#pragma unroll
    for (int fc = 0; fc < 4; fc++) {
      int n = rt * 64 + wr * 32 + fr * 16 + ks * 4;
      int g = wc * 64 + fc * 16 + lr;
#pragma unroll
      for (int q = 0; q < 4; q++) op[(size_t)(n + q) * Gx + g] = f2h(acc[fr][fc][q]);
    }
}

// ---------------------------------------------------------------------------
// attn4: scores[i][j] = sum_g xT16[i][g]*WxT16[j][g] (fp16 MFMA);
// leaky, mask (bitmap), softmax over j, direct ushort4 store aijT[j][i] bf16.
// grid (B*P, N/64), 512 thr (2 wr x 4 wc waves). Block: 64 i x 512 j, K=128.
// ---------------------------------------------------------------------------
__global__ __launch_bounds__(512) void attn4_kernel(const u16* __restrict__ xT16,
                                                    const u16* __restrict__ WxT16,
                                                    const u32* __restrict__ mb,
                                                    u16* __restrict__ aijT) {
  __shared__ __align__(16) char smem[55296];
  constexpr int OB = 16384, OMBS = 49152, ORED = 53248;
  const int bp = blockIdx.x, b = bp >> 2;
  const int i0 = blockIdx.y * 64;
  const int tid = threadIdx.x;
  const int w = tid >> 6, l = tid & 63;
  const int wr = w >> 2, wc = w & 3;
  const int lr = l & 15, ks = l >> 4;

  {  // mask rows -> LDS (64 rows x 16 words)
    const u32* mbp = mb + ((size_t)b * Nx + i0) * 16;
    u32* mbs = (u32*)(smem + OMBS);
    mbs[tid] = mbp[tid];
    mbs[tid + 512] = mbp[tid + 512];
  }
  {  // stage A: xT16 rows i0..i0+63, full K=128, chunk-XOR (r&15)
    const u16* Ap = xT16 + ((size_t)b * Nx + i0) * Gx;
#pragma unroll
    for (int it = 0; it < 2; it++) {
      int chunk = it * 512 + w * 64 + l;
      int r = chunk >> 4, kq = l & 15;
      int kg = (kq ^ (r & 15)) * 8;
      G2L16(Ap + (size_t)r * Gx + kg, smem + it * 8192 + w * 1024);
    }
  }

  v4f acc[2][8];
#pragma unroll
  for (int fr = 0; fr < 2; fr++)
#pragma unroll
    for (int fc = 0; fc < 8; fc++) acc[fr][fc] = (v4f){0.f, 0.f, 0.f, 0.f};

  const u16* Bp = WxT16 + (size_t)bp * Nx * Gx;
  for (int g0 = 0; g0 < Gx; g0 += 32) {
    __syncthreads();
#pragma unroll
    for (int it = 0; it < 4; it++) {
      int chunk = it * 512 + w * 64 + l;
      int r = chunk >> 2, kq = l & 3;
      int kg = (kq ^ (r & 3)) * 8;
      G2L16(Bp + (size_t)r * Gx + g0 + kg, smem + OB + it * 8192 + w * 1024);
    }
    __syncthreads();
    int kk = (g0 >> 3) + ks;
    v8hf ah[2];
#pragma unroll
    for (int fr = 0; fr < 2; fr++) {
      int ra = wr * 32 + fr * 16 + lr;
      ah[fr] = *(const v8hf*)(smem + ra * 256 + ((kk ^ (ra & 15)) * 16));
    }
#pragma unroll
    for (int fc = 0; fc < 8; fc++) {
      int rb = wc * 128 + fc * 16 + lr;
      v8hf bh = *(const v8hf*)(smem + OB + rb * 64 + ((ks ^ (rb & 3)) * 16));
#pragma unroll
      for (int fr = 0; fr < 2; fr++)
        acc[fr][fc] = __builtin_amdgcn_mfma_f32_16x16x32_f16(ah[fr], bh, acc[fr][fc], 0, 0, 0);
    }
  }

  u32* mbs = (u32*)(smem + OMBS);
  float* red0 = (float*)(smem + ORED);
  float* red1 = red0 + 256;

  // pass 1: masked leaky-relu + cross-wave row max partials
#pragma unroll
  for (int fr = 0; fr < 2; fr++)
#pragma unroll
    for (int q = 0; q < 4; q++) {
      int row = wr * 32 + fr * 16 + ks * 4 + q;
      float m = -BIGF;
#pragma unroll
      for (int fc = 0; fc < 8; fc++) {
        u32 word = mbs[row * 16 + wc * 4 + (fc >> 1)];
        int bit = ((fc & 1) << 4) + lr;
        float v = acc[fr][fc][q];
        v = v >= 0.f ? v : NEG_SLOPE * v;
        v = ((word >> bit) & 1u) ? v : -BIGF;
        acc[fr][fc][q] = v;
        m = fmaxf(m, v);
      }
      m = fmaxf(m, __shfl_xor(m, 1, 64));
      m = fmaxf(m, __shfl_xor(m, 2, 64));
      m = fmaxf(m, __shfl_xor(m, 4, 64));
      m = fmaxf(m, __shfl_xor(m, 8, 64));
      if (lr == 0) red0[row * 4 + wc] = m;
    }
  __syncthreads();
  // pass 2: global max, exp, cross-wave row sum partials
#pragma unroll
  for (int fr = 0; fr < 2; fr++)
#pragma unroll
    for (int q = 0; q < 4; q++) {
      int row = wr * 32 + fr * 16 + ks * 4 + q;
      float4 pm = *(const float4*)&red0[row * 4];
      float gm = fmaxf(fmaxf(pm.x, pm.y), fmaxf(pm.z, pm.w));
      float s = 0.f;
#pragma unroll
      for (int fc = 0; fc < 8; fc++) {
        float v = acc[fr][fc][q];
        float e = (v <= -0.5f * BIGF) ? 0.f : __expf(v - gm);
        acc[fr][fc][q] = e;
        s += e;
      }
      s += __shfl_xor(s, 1, 64);
      s += __shfl_xor(s, 2, 64);
      s += __shfl_xor(s, 4, 64);
      s += __shfl_xor(s, 8, 64);
      if (lr == 0) red1[row * 4 + wc] = s;
    }
  __syncthreads();
  // pass 3: normalize + direct ushort4 stores (4 consecutive i per lane)
  u16* dst = aijT + (size_t)bp * Nx * Nx + i0;
#pragma unroll
  for (int fr = 0; fr < 2; fr++) {
    int rbase = wr * 32 + fr * 16 + ks * 4;
    float inv[4];
#pragma unroll
    for (int q = 0; q < 4; q++) {
      float4 ps = *(const float4*)&red1[(rbase + q) * 4];
      float tot = (ps.x + ps.y) + (ps.z + ps.w);
      inv[q] = tot > 0.f ? 1.f / tot : 0.f;
    }
#pragma unroll
    for (int fc = 0; fc < 8; fc++) {
      int j = wc * 128 + fc * 16 + lr;
      ushort4 pk;
      pk.x = f2b(acc[fr][fc][0] * inv[0]);
      pk.y = f2b(acc[fr][fc][1] * inv[1]);
      pk.z = f2b(acc[fr][fc][2] * inv[2]);
      pk.w = f2b(acc[fr][fc][3] * inv[3]);
      *(ushort4*)&dst[(size_t)j * Nx + rbase] = pk;
    }
  }
}

// ---------------------------------------------------------------------------
// NT-GEMM core: C[r][c] = sum_k A[r][k]*B[c][k] (bf16, fp32 acc).
// ROUND-3 proven structure: stage -> barrier -> compute, 2 barriers / k-step.
// MODE 0: hop1  A=aijT(bp)  B=xb(b)    -> z1[g][m] + z1T[m][g]
// MODE 1: hop2  A=z1(bp)    B=aijT(bp) -> z2T[m][g]
// MODE 2: filt  A={xTb,z1T,z2T} segs  B=Hb(p) -> out[f][n] fp32 (+bias, relu)
// ---------------------------------------------------------------------------
template <int MODE>
__global__ __launch_bounds__(256) void gnt_kernel(const u16* __restrict__ pA,
                                                  const u16* __restrict__ pB,
                                                  const u16* __restrict__ pC,
                                                  const u16* __restrict__ pHb,
                                                  u16* __restrict__ o1,
                                                  u16* __restrict__ o2,
                                                  float* __restrict__ oF,
                                                  const float* __restrict__ bias) {
  __shared__ __align__(16) char smem[4096 + 8192];
  const int bp = blockIdx.x;
  const int b = bp >> 2, p = bp & 3;
  const int by = blockIdx.y;
  const int rt = (MODE == 1) ? (by >> 2) : by;
  const int ct = (MODE == 1) ? (by & 3) : 0;
  const int tid = threadIdx.x;
  const int w = tid >> 6, l = tid & 63;
  const int wr = w >> 1, wc = w & 1;
  const int lr = l & 15, kslot = l >> 4;

  constexpr int KTOT = (MODE == 2) ? (Kx * Gx) : Nx;
  constexpr int SA = (MODE == 2) ? Gx : Nx;
  constexpr int SB = (MODE == 2) ? (Kx * Gx) : Nx;

  const u16* Abase;
  const u16* Bbase;
  if (MODE == 0) {
    Abase = pA + (size_t)bp * Nx * Nx + (size_t)rt * 64 * Nx;
    Bbase = pB + (size_t)b * Gx * Nx;
  } else if (MODE == 1) {
    Abase = pA + (size_t)bp * Gx * Nx + (size_t)rt * 64 * Nx;
    Bbase = pB + (size_t)bp * Nx * Nx + (size_t)ct * 128 * Nx;
  } else {
    Abase = nullptr;
    Bbase = pHb + (size_t)p * Fx * (Kx * Gx);
  }

  const int sar = tid >> 2, sakq = tid & 3;
  const int sakg = sakq ^ (sar & 3);
  const int sbr0 = tid >> 2, sbkg0 = (tid & 3) ^ (sbr0 & 3);
  const int sbr1 = (tid + 256) >> 2, sbkg1 = (tid & 3) ^ (sbr1 & 3);
  char* ldsAdst = smem + w * 1024;
  char* ldsBdst0 = smem + 4096 + w * 1024;
  char* ldsBdst1 = smem + 4096 + 4096 + w * 1024;

  int aoff[2], boff[4];
#pragma unroll
  for (int fr = 0; fr < 2; fr++) {
    int row = wr * 32 + fr * 16 + lr;
    aoff[fr] = row * 64 + ((kslot ^ (row & 3)) * 16);
  }
#pragma unroll
  for (int fc = 0; fc < 4; fc++) {
    int row = wc * 64 + fc * 16 + lr;
    boff[fc] = 4096 + row * 64 + ((kslot ^ (row & 3)) * 16);
  }

  v4f acc[2][4];
#pragma unroll
  for (int fr = 0; fr < 2; fr++)
#pragma unroll
    for (int fc = 0; fc < 4; fc++) acc[fr][fc] = (v4f){0.f, 0.f, 0.f, 0.f};

  for (int k0 = 0; k0 < KTOT; k0 += 32) {
    const u16* Aseg;
    int kin;
    if (MODE == 2) {
      int seg = k0 >> 7;
      kin = k0 & 127;
      const u16* base = (seg == 0) ? (pA + (size_t)b * Nx * Gx)
                       : (seg == 1) ? (pB + (size_t)bp * Nx * Gx)
                                    : (pC + (size_t)bp * Nx * Gx);
      Aseg = base + (size_t)rt * 64 * Gx;
    } else {
      Aseg = Abase;
      kin = k0;
    }
    __syncthreads();
    G2L16(Aseg + (size_t)sar * SA + kin + sakg * 8, ldsAdst);
    G2L16(Bbase + (size_t)sbr0 * SB + k0 + sbkg0 * 8, ldsBdst0);
    G2L16(Bbase + (size_t)sbr1 * SB + k0 + sbkg1 * 8, ldsBdst1);
    __syncthreads();

    v8bf af[2], bf4[4];
#pragma unroll
    for (int fr = 0; fr < 2; fr++) af[fr] = *(const v8bf*)(smem + aoff[fr]);
#pragma unroll
    for (int fc = 0; fc < 4; fc++) bf4[fc] = *(const v8bf*)(smem + boff[fc]);
#pragma unroll
    for (int fr = 0; fr < 2; fr++)
#pragma unroll
      for (int fc = 0; fc < 4; fc++)
        acc[fr][fc] = __builtin_amdgcn_mfma_f32_16x16x32_bf16(af[fr], bf4[fc],
                                                              acc[fr][fc], 0, 0, 0);
  }

  if (MODE == 0) {
    u16* z1p = o1 + (size_t)bp * Gx * Nx;
    u16* z1Tp = o2 + (size_t)bp * Nx * Gx;
#pragma unroll
    for (int fr = 0; fr < 2; fr++)
#pragma unroll
      for (int fc = 0; fc < 4; fc++) {
        int m0 = rt * 64 + wr * 32 + fr * 16 + kslot * 4;
        int g = wc * 64 + fc * 16 + lr;
        v4f a = acc[fr][fc];
        ushort4 pk;
        pk.x = f2b(a[0]); pk.y = f2b(a[1]); pk.z = f2b(a[2]); pk.w = f2b(a[3]);
        *(ushort4*)&z1p[(size_t)g * Nx + m0] = pk;
        z1Tp[(size_t)(m0 + 0) * Gx + g] = pk.x;
        z1Tp[(size_t)(m0 + 1) * Gx + g] = pk.y;
        z1Tp[(size_t)(m0 + 2) * Gx + g] = pk.z;
        z1Tp[(size_t)(m0 + 3) * Gx + g] = pk.w;
      }
  } else if (MODE == 1) {
    u16* z2Tp = o1 + (size_t)bp * Nx * Gx;
#pragma unroll
    for (int fr = 0; fr < 2; fr++)
#pragma unroll
      for (int fc = 0; fc < 4; fc++) {
        int g0r = rt * 64 + wr * 32 + fr * 16 + kslot * 4;
        int m = ct * 128 + wc * 64 + fc * 16 + lr;
        v4f a = acc[fr][fc];
        ushort4 pk;
        pk.x = f2b(a[0]); pk.y = f2b(a[1]); pk.z = f2b(a[2]); pk.w = f2b(a[3]);
        *(ushort4*)&z2Tp[(size_t)m * Gx + g0r] = pk;
      }
  } else {
    float* op = oF + (size_t)(b * Px + p) * Fx * Nx;
#pragma unroll
    for (int fc = 0; fc < 4; fc++) {
      int f = wc * 64 + fc * 16 + lr;
      float bi = bias[f];
#pragma unroll
      for (int fr = 0; fr < 2; fr++) {
        int n0 = rt * 64 + wr * 32 + fr * 16 + kslot * 4;
        v4f a = acc[fr][fc];
        float4 o;
        o.x = fmaxf(a[0] + bi, 0.f);
        o.y = fmaxf(a[1] + bi, 0.f);
        o.z = fmaxf(a[2] + bi, 0.f);
        o.w = fmaxf(a[3] + bi, 0.f);
        *(float4*)&op[(size_t)f * Nx + n0] = o;
      }
    }
  }
}

// ---------------------------------------------------------------------------
extern "C" void kernel_launch(void* const* d_in, const int* in_sizes, int n_in,
                              void* d_out, int out_size, void* d_ws, size_t ws_size,
                              hipStream_t stream) {
  const float* x = (const float*)d_in[0];
  const float* S = (const float*)d_in[1];
  const float* W = (const float*)d_in[2];
  const float* h = (const float*)d_in[4];
  const float* bias = (const float*)d_in[5];
  float* out = (float*)d_out;

  char* ws = (char*)d_ws;
  // sizes: aijT 32MB | WxT16 8MB (B*P*N*G*2 = 8,388,608 -- was wrongly 4MB) |
  // xT16/xTb/xb 2MB each | z1/z1T/z2T 8MB each | Hb 384KB | W16 128KB | mb 512KB
  u16* aijT  = (u16*)ws;                   // @ 0          33,554,432
  u16* WxT16 = (u16*)(ws + 33554432);      // @ 32M         8,388,608
  u16* xT16  = (u16*)(ws + 41943040);      // @ 40M         2,097,152
  u16* xTb   = (u16*)(ws + 44040192);      // @ 42M         2,097,152
  u16* xb    = (u16*)(ws + 46137344);      // @ 44M         2,097,152
  u16* z1    = (u16*)(ws + 48234496);      // @ 46M         8,388,608
  u16* z1T   = (u16*)(ws + 56623104);      // @ 54M         8,388,608
  u16* z2T   = (u16*)(ws + 65011712);      // @ 62M         8,388,608
  u16* Hb    = (u16*)(ws + 73400320);      // @ 70M           393,216
  u16* W16   = (u16*)(ws + 73793536);      //                 131,072
  u32* mb    = (u32*)(ws + 73924608);      //                 524,288

  mask_kernel<<<dim3((Bx * Nx * Nx / 32) / 256), 256, 0, stream>>>(S, mb);
  castx3_kernel<<<dim3(Gx / 32, Nx / 32, Bx), 256, 0, stream>>>(x, xb, xTb, xT16);
  castw16_kernel<<<dim3(Px * Gx * Gx / 1024), 256, 0, stream>>>(W, W16);
  casth_kernel<<<dim3(Px * Fx * Kx * Gx / 1024), 256, 0, stream>>>(h, Hb);
  wxt16_kernel<<<dim3(Bx * Px, Nx / 64), 256, 0, stream>>>(xT16, W16, WxT16);
  attn4_kernel<<<dim3(Bx * Px, Nx / 64), 512, 0, stream>>>(xT16, WxT16, mb, aijT);
  gnt_kernel<0><<<dim3(Bx * Px, 8), 256, 0, stream>>>(aijT, xb, nullptr, nullptr,
                                                      z1, z1T, nullptr, nullptr);
  gnt_kernel<1><<<dim3(Bx * Px, 8), 256, 0, stream>>>(z1, aijT, nullptr, nullptr,
                                                      z2T, nullptr, nullptr, nullptr);
  gnt_kernel<2><<<dim3(Bx * Px, 8), 256, 0, stream>>>(xTb, z1T, z2T, Hb,
                                                      nullptr, nullptr, out, bias);
  (void)in_sizes; (void)n_in; (void)out_size; (void)ws_size;
}

// Round 7
// 77.138 us; speedup vs baseline: 5.3166x; 1.0532x over previous
//
#include <hip/hip_runtime.h>

#define Bx 16
#define Gx 128
#define Nx 512
#define Px 4
#define Kx 3
#define Fx 128
#define NEG_SLOPE 0.2f
#define ZERO_TOL 1e-9f
#define BIGF 1.0e30f

typedef unsigned short u16;
typedef unsigned int u32;
typedef __bf16 v8bf __attribute__((ext_vector_type(8)));
typedef _Float16 v8hf __attribute__((ext_vector_type(8)));
typedef float v4f __attribute__((ext_vector_type(4)));

__device__ __forceinline__ u16 f2b(float f) {
  union { float f; u32 u; } v; v.f = f;
  u32 r = (v.u + 0x7fffu + ((v.u >> 16) & 1u)) >> 16;
  return (u16)r;
}
__device__ __forceinline__ u16 f2h(float f) {
  union { _Float16 h; u16 u; } v; v.h = (_Float16)f;
  return v.u;
}

// async global->LDS, 16B per lane; LDS dst must be wave-uniform base (+lane*16)
#define G2L16(gsrc, ldst)                                                     \
  __builtin_amdgcn_global_load_lds(                                           \
      (const __attribute__((address_space(1))) void*)(gsrc),                  \
      (__attribute__((address_space(3))) void*)(ldst), 16, 0, 0)

// ---------------------------------------------------------------------------
// prep: fused {mask | castx3 | castw16 | casth} by block range.
// blocks: [0,512) mask, [512,1536) castx3, [1536,1600) castw16, [1600,1792) casth
// ---------------------------------------------------------------------------
__global__ __launch_bounds__(256) void prep_kernel(const float* __restrict__ S,
                                                   const float* __restrict__ x,
                                                   const float* __restrict__ W,
                                                   const float* __restrict__ h,
                                                   u32* __restrict__ mb,
                                                   u16* __restrict__ xb,
                                                   u16* __restrict__ xTb,
                                                   u16* __restrict__ xT16,
                                                   u16* __restrict__ w16,
                                                   u16* __restrict__ Hb) {
  const int blk = blockIdx.x;
  const int tid = threadIdx.x;
  __shared__ float t[32][33];
  if (blk < 512) {
    // ---- mask: bit j of mb[(b*N+i)*16 + j/32] = |S[b,0,i,j]| > tol
    const int wi = blk * 256 + tid;
    const float4* S4 = (const float4*)S;
    u32 bits = 0;
#pragma unroll
    for (int q = 0; q < 8; q++) {
      float4 v = S4[(size_t)wi * 8 + q];
      bits |= (fabsf(v.x) > ZERO_TOL ? 1u : 0u) << (q * 4);
      bits |= (fabsf(v.y) > ZERO_TOL ? 2u : 0u) << (q * 4);
      bits |= (fabsf(v.z) > ZERO_TOL ? 4u : 0u) << (q * 4);
      bits |= (fabsf(v.w) > ZERO_TOL ? 8u : 0u) << (q * 4);
    }
    mb[wi] = bits;
  } else if (blk < 1536) {
    // ---- castx3: x -> xb (bf16 [b][g][n]), xTb/xT16 ([b][n][g])
    const int idx = blk - 512;
    const int b = idx >> 6, g0 = ((idx >> 4) & 3) * 32, n0 = (idx & 15) * 32;
    const int r = tid >> 3, c4 = (tid & 7) * 4;
    const float* xp = x + (size_t)b * Gx * Nx;
    float4 v = *(const float4*)&xp[(g0 + r) * Nx + n0 + c4];
    ushort4 o;
    o.x = f2b(v.x); o.y = f2b(v.y); o.z = f2b(v.z); o.w = f2b(v.w);
    *(ushort4*)&xb[(size_t)b * Gx * Nx + (g0 + r) * Nx + n0 + c4] = o;
    t[r][c4 + 0] = v.x; t[r][c4 + 1] = v.y; t[r][c4 + 2] = v.z; t[r][c4 + 3] = v.w;
    __syncthreads();
    float tv[4] = {t[c4 + 0][r], t[c4 + 1][r], t[c4 + 2][r], t[c4 + 3][r]};
    ushort4 ob, oh;
    ob.x = f2b(tv[0]); oh.x = f2h(tv[0]);
    ob.y = f2b(tv[1]); oh.y = f2h(tv[1]);
    ob.z = f2b(tv[2]); oh.z = f2h(tv[2]);
    ob.w = f2b(tv[3]); oh.w = f2h(tv[3]);
    size_t off = (size_t)b * Nx * Gx + (size_t)(n0 + r) * Gx + g0 + c4;
    *(ushort4*)&xTb[off] = ob;
    *(ushort4*)&xT16[off] = oh;
  } else if (blk < 1600) {
    // ---- castw16: W -> fp16
    int i4 = ((blk - 1536) * 256 + tid) * 4;
    float4 v = *(const float4*)&W[i4];
    ushort4 o;
    o.x = f2h(v.x); o.y = f2h(v.y); o.z = f2h(v.z); o.w = f2h(v.w);
    *(ushort4*)&w16[i4] = o;
  } else {
    // ---- casth: h -> bf16
    int i4 = ((blk - 1600) * 256 + tid) * 4;
    float4 v = *(const float4*)&h[i4];
    ushort4 o;
    o.x = f2b(v.x); o.y = f2b(v.y); o.z = f2b(v.z); o.w = f2b(v.w);
    *(ushort4*)&Hb[i4] = o;
  }
}

// ---------------------------------------------------------------------------
// wxt16: WxT[n][g] = sum_h xT[n][h] * W[g][h]  (fp16 MFMA, fp32 acc, fp16 out)
// grid (B*P, N/64), 256 thr (2x2 waves), block 64n x 128g, K=128 single-stage.
// ---------------------------------------------------------------------------
__global__ __launch_bounds__(256) void wxt16_kernel(const u16* __restrict__ xT16,
                                                    const u16* __restrict__ w16,
                                                    u16* __restrict__ WxT16) {
  __shared__ __align__(16) char smem[49152];
  constexpr int OB = 16384;
  const int bp = blockIdx.x, b = bp >> 2, p = bp & 3;
  const int rt = blockIdx.y;
  const int tid = threadIdx.x;
  const int w = tid >> 6, l = tid & 63;
  const int wr = w >> 1, wc = w & 1;
  const int lr = l & 15, ks = l >> 4;

  const u16* Ap = xT16 + ((size_t)b * Nx + rt * 64) * Gx;
  const u16* Bp = w16 + (size_t)p * Gx * Gx;
#pragma unroll
  for (int it = 0; it < 4; it++) {
    int chunk = it * 256 + w * 64 + l;
    int r = chunk >> 4, kq = l & 15;
    int kg = (kq ^ (r & 15)) * 8;
    G2L16(Ap + (size_t)r * Gx + kg, smem + it * 4096 + w * 1024);
  }
#pragma unroll
  for (int it = 0; it < 8; it++) {
    int chunk = it * 256 + w * 64 + l;
    int r = chunk >> 4, kq = l & 15;
    int kg = (kq ^ (r & 15)) * 8;
    G2L16(Bp + (size_t)r * Gx + kg, smem + OB + it * 4096 + w * 1024);
  }
  __syncthreads();

  v4f acc[2][4];
#pragma unroll
  for (int fr = 0; fr < 2; fr++)
#pragma unroll
    for (int fc = 0; fc < 4; fc++) acc[fr][fc] = (v4f){0.f, 0.f, 0.f, 0.f};

#pragma unroll
  for (int t = 0; t < 4; t++) {
    int kk = t * 4 + ks;
    v8hf ah[2];
#pragma unroll
    for (int fr = 0; fr < 2; fr++) {
      int ra = wr * 32 + fr * 16 + lr;
      ah[fr] = *(const v8hf*)(smem + ra * 256 + ((kk ^ (ra & 15)) * 16));
    }
#pragma unroll
    for (int fc = 0; fc < 4; fc++) {
      int rb = wc * 64 + fc * 16 + lr;
      v8hf bh = *(const v8hf*)(smem + OB + rb * 256 + ((kk ^ (rb & 15)) * 16));
#pragma unroll
      for (int fr = 0; fr < 2; fr++)
        acc[fr][fc] = __builtin_amdgcn_mfma_f32_16x16x32_f16(ah[fr], bh, acc[fr][fc], 0, 0, 0);
    }
  }

  u16* op = WxT16 + (size_t)bp * Nx * Gx;
#pragma unroll
  for (int fr = 0; fr < 2; fr++)
#pragma unroll
    for (int fc = 0; fc < 4; fc++) {
      int n = rt * 64 + wr * 32 + fr * 16 + ks * 4;
      int g = wc * 64 + fc * 16 + lr;
#pragma unroll
      for (int q = 0; q < 4; q++) op[(size_t)(n + q) * Gx + g] = f2h(acc[fr][fc][q]);
    }
}

// ---------------------------------------------------------------------------
// attn4: scores[i][j] = sum_g xT16[i][g]*WxT16[j][g] (fp16 MFMA);
// leaky, mask (bitmap), softmax over j, direct ushort4 store aijT[j][i] bf16.
// grid (B*P, N/64), 512 thr (2 wr x 4 wc waves). Block: 64 i x 512 j, K=128.
// ---------------------------------------------------------------------------
__global__ __launch_bounds__(512) void attn4_kernel(const u16* __restrict__ xT16,
                                                    const u16* __restrict__ WxT16,
                                                    const u32* __restrict__ mb,
                                                    u16* __restrict__ aijT) {
  __shared__ __align__(16) char smem[55296];
  constexpr int OB = 16384, OMBS = 49152, ORED = 53248;
  const int bp = blockIdx.x, b = bp >> 2;
  const int i0 = blockIdx.y * 64;
  const int tid = threadIdx.x;
  const int w = tid >> 6, l = tid & 63;
  const int wr = w >> 2, wc = w & 3;
  const int lr = l & 15, ks = l >> 4;

  {  // mask rows -> LDS (64 rows x 16 words)
    const u32* mbp = mb + ((size_t)b * Nx + i0) * 16;
    u32* mbs = (u32*)(smem + OMBS);
    mbs[tid] = mbp[tid];
    mbs[tid + 512] = mbp[tid + 512];
  }
  {  // stage A: xT16 rows i0..i0+63, full K=128, chunk-XOR (r&15)
    const u16* Ap = xT16 + ((size_t)b * Nx + i0) * Gx;
#pragma unroll
    for (int it = 0; it < 2; it++) {
      int chunk = it * 512 + w * 64 + l;
      int r = chunk >> 4, kq = l & 15;
      int kg = (kq ^ (r & 15)) * 8;
      G2L16(Ap + (size_t)r * Gx + kg, smem + it * 8192 + w * 1024);
    }
  }

  v4f acc[2][8];
#pragma unroll
  for (int fr = 0; fr < 2; fr++)
#pragma unroll
    for (int fc = 0; fc < 8; fc++) acc[fr][fc] = (v4f){0.f, 0.f, 0.f, 0.f};

  const u16* Bp = WxT16 + (size_t)bp * Nx * Gx;
  for (int g0 = 0; g0 < Gx; g0 += 32) {
    __syncthreads();
#pragma unroll
    for (int it = 0; it < 4; it++) {
      int chunk = it * 512 + w * 64 + l;
      int r = chunk >> 2, kq = l & 3;
      int kg = (kq ^ (r & 3)) * 8;
      G2L16(Bp + (size_t)r * Gx + g0 + kg, smem + OB + it * 8192 + w * 1024);
    }
    __syncthreads();
    int kk = (g0 >> 3) + ks;
    v8hf ah[2];
#pragma unroll
    for (int fr = 0; fr < 2; fr++) {
      int ra = wr * 32 + fr * 16 + lr;
      ah[fr] = *(const v8hf*)(smem + ra * 256 + ((kk ^ (ra & 15)) * 16));
    }
#pragma unroll
    for (int fc = 0; fc < 8; fc++) {
      int rb = wc * 128 + fc * 16 + lr;
      v8hf bh = *(const v8hf*)(smem + OB + rb * 64 + ((ks ^ (rb & 3)) * 16));
#pragma unroll
      for (int fr = 0; fr < 2; fr++)
        acc[fr][fc] = __builtin_amdgcn_mfma_f32_16x16x32_f16(ah[fr], bh, acc[fr][fc], 0, 0, 0);
    }
  }

  u32* mbs = (u32*)(smem + OMBS);
  float* red0 = (float*)(smem + ORED);
  float* red1 = red0 + 256;

  // pass 1: masked leaky-relu + cross-wave row max partials
#pragma unroll
  for (int fr = 0; fr < 2; fr++)
#pragma unroll
    for (int q = 0; q < 4; q++) {
      int row = wr * 32 + fr * 16 + ks * 4 + q;
      float m = -BIGF;
#pragma unroll
      for (int fc = 0; fc < 8; fc++) {
        u32 word = mbs[row * 16 + wc * 4 + (fc >> 1)];
        int bit = ((fc & 1) << 4) + lr;
        float v = acc[fr][fc][q];
        v = v >= 0.f ? v : NEG_SLOPE * v;
        v = ((word >> bit) & 1u) ? v : -BIGF;
        acc[fr][fc][q] = v;
        m = fmaxf(m, v);
      }
      m = fmaxf(m, __shfl_xor(m, 1, 64));
      m = fmaxf(m, __shfl_xor(m, 2, 64));
      m = fmaxf(m, __shfl_xor(m, 4, 64));
      m = fmaxf(m, __shfl_xor(m, 8, 64));
      if (lr == 0) red0[row * 4 + wc] = m;
    }
  __syncthreads();
  // pass 2: global max, exp, cross-wave row sum partials
#pragma unroll
  for (int fr = 0; fr < 2; fr++)
#pragma unroll
    for (int q = 0; q < 4; q++) {
      int row = wr * 32 + fr * 16 + ks * 4 + q;
      float4 pm = *(const float4*)&red0[row * 4];
      float gm = fmaxf(fmaxf(pm.x, pm.y), fmaxf(pm.z, pm.w));
      float s = 0.f;
#pragma unroll
      for (int fc = 0; fc < 8; fc++) {
        float v = acc[fr][fc][q];
        float e = (v <= -0.5f * BIGF) ? 0.f : __expf(v - gm);
        acc[fr][fc][q] = e;
        s += e;
      }
      s += __shfl_xor(s, 1, 64);
      s += __shfl_xor(s, 2, 64);
      s += __shfl_xor(s, 4, 64);
      s += __shfl_xor(s, 8, 64);
      if (lr == 0) red1[row * 4 + wc] = s;
    }
  __syncthreads();
  // pass 3: normalize + direct ushort4 stores (4 consecutive i per lane)
  u16* dst = aijT + (size_t)bp * Nx * Nx + i0;
#pragma unroll
  for (int fr = 0; fr < 2; fr++) {
    int rbase = wr * 32 + fr * 16 + ks * 4;
    float inv[4];
#pragma unroll
    for (int q = 0; q < 4; q++) {
      float4 ps = *(const float4*)&red1[(rbase + q) * 4];
      float tot = (ps.x + ps.y) + (ps.z + ps.w);
      inv[q] = tot > 0.f ? 1.f / tot : 0.f;
    }
#pragma unroll
    for (int fc = 0; fc < 8; fc++) {
      int j = wc * 128 + fc * 16 + lr;
      ushort4 pk;
      pk.x = f2b(acc[fr][fc][0] * inv[0]);
      pk.y = f2b(acc[fr][fc][1] * inv[1]);
      pk.z = f2b(acc[fr][fc][2] * inv[2]);
      pk.w = f2b(acc[fr][fc][3] * inv[3]);
      *(ushort4*)&dst[(size_t)j * Nx + rbase] = pk;
    }
  }
}

// ---------------------------------------------------------------------------
// NT-GEMM core: C[r][c] = sum_k A[r][k]*B[c][k] (bf16, fp32 acc), 2-phase
// double-buffered: stage tile t+1 before computing tile t, ONE barrier/iter.
// Ordering: barrier at iter t implicitly drains vmcnt(0) (tile t staged) AND
// guarantees all waves finished ds_reads of the buffer STAGE(t+1) overwrites.
// MODE 0: hop1  A=aijT(bp)  B=xb(b)    -> z1[g][m] + z1T[m][g]
// MODE 1: hop2  A=z1(bp)    B=aijT(bp) -> z2T[m][g]
// MODE 2: filt  A={xTb,z1T,z2T} segs  B=Hb(p) -> out[f][n] fp32 (+bias, relu)
// ---------------------------------------------------------------------------
template <int MODE>
__global__ __launch_bounds__(256) void gnt_kernel(const u16* __restrict__ pA,
                                                  const u16* __restrict__ pB,
                                                  const u16* __restrict__ pC,
                                                  const u16* __restrict__ pHb,
                                                  u16* __restrict__ o1,
                                                  u16* __restrict__ o2,
                                                  float* __restrict__ oF,
                                                  const float* __restrict__ bias) {
  __shared__ __align__(16) char smem[2][12288];
  const int bp = blockIdx.x;
  const int b = bp >> 2, p = bp & 3;
  const int by = blockIdx.y;
  const int rt = (MODE == 1) ? (by >> 2) : by;
  const int ct = (MODE == 1) ? (by & 3) : 0;
  const int tid = threadIdx.x;
  const int w = tid >> 6, l = tid & 63;
  const int wr = w >> 1, wc = w & 1;
  const int lr = l & 15, kslot = l >> 4;

  constexpr int KTOT = (MODE == 2) ? (Kx * Gx) : Nx;
  constexpr int SA = (MODE == 2) ? Gx : Nx;
  constexpr int SB = (MODE == 2) ? (Kx * Gx) : Nx;
  constexpr int NT = KTOT / 32;

  const u16* Abase;
  const u16* Bbase;
  if (MODE == 0) {
    Abase = pA + (size_t)bp * Nx * Nx + (size_t)rt * 64 * Nx;
    Bbase = pB + (size_t)b * Gx * Nx;
  } else if (MODE == 1) {
    Abase = pA + (size_t)bp * Gx * Nx + (size_t)rt * 64 * Nx;
    Bbase = pB + (size_t)bp * Nx * Nx + (size_t)ct * 128 * Nx;
  } else {
    Abase = nullptr;
    Bbase = pHb + (size_t)p * Fx * (Kx * Gx);
  }

  const int sar = tid >> 2;
  const int sakg = (tid & 3) ^ (sar & 3);
  const int sbr0 = tid >> 2, sbkg0 = (tid & 3) ^ (sbr0 & 3);
  const int sbr1 = (tid + 256) >> 2, sbkg1 = (tid & 3) ^ (sbr1 & 3);

  int aoff[2], boff[4];
#pragma unroll
  for (int fr = 0; fr < 2; fr++) {
    int row = wr * 32 + fr * 16 + lr;
    aoff[fr] = row * 64 + ((kslot ^ (row & 3)) * 16);
  }
#pragma unroll
  for (int fc = 0; fc < 4; fc++) {
    int row = wc * 64 + fc * 16 + lr;
    boff[fc] = 4096 + row * 64 + ((kslot ^ (row & 3)) * 16);
  }

  auto STAGE = [&](int bufi, int k0) {
    const u16* Aseg;
    int kin;
    if (MODE == 2) {
      int seg = k0 >> 7;
      kin = k0 & 127;
      const u16* base = (seg == 0) ? (pA + (size_t)b * Nx * Gx)
                       : (seg == 1) ? (pB + (size_t)bp * Nx * Gx)
                                    : (pC + (size_t)bp * Nx * Gx);
      Aseg = base + (size_t)rt * 64 * Gx;
    } else {
      Aseg = Abase;
      kin = k0;
    }
    char* base = smem[bufi];
    G2L16(Aseg + (size_t)sar * SA + kin + sakg * 8, base + w * 1024);
    G2L16(Bbase + (size_t)sbr0 * SB + k0 + sbkg0 * 8, base + 4096 + w * 1024);
    G2L16(Bbase + (size_t)sbr1 * SB + k0 + sbkg1 * 8, base + 8192 + w * 1024);
  };

  v4f acc[2][4];
#pragma unroll
  for (int fr = 0; fr < 2; fr++)
#pragma unroll
    for (int fc = 0; fc < 4; fc++) acc[fr][fc] = (v4f){0.f, 0.f, 0.f, 0.f};

  STAGE(0, 0);
  int cur = 0;
  for (int t = 0; t < NT; t++) {
    __syncthreads();  // drains vmcnt(0): tile t landed; prev reads all done
    if (t + 1 < NT) STAGE(cur ^ 1, (t + 1) * 32);
    const char* bb = smem[cur];
    v8bf af[2], bf4[4];
#pragma unroll
    for (int fr = 0; fr < 2; fr++) af[fr] = *(const v8bf*)(bb + aoff[fr]);
#pragma unroll
    for (int fc = 0; fc < 4; fc++) bf4[fc] = *(const v8bf*)(bb + boff[fc]);
#pragma unroll
    for (int fr = 0; fr < 2; fr++)
#pragma unroll
      for (int fc = 0; fc < 4; fc++)
        acc[fr][fc] = __builtin_amdgcn_mfma_f32_16x16x32_bf16(af[fr], bf4[fc],
                                                              acc[fr][fc], 0, 0, 0);
    cur ^= 1;
  }

  if (MODE == 0) {
    u16* z1p = o1 + (size_t)bp * Gx * Nx;
    u16* z1Tp = o2 + (size_t)bp * Nx * Gx;
#pragma unroll
    for (int fr = 0; fr < 2; fr++)
#pragma unroll
      for (int fc = 0; fc < 4; fc++) {
        int m0 = rt * 64 + wr * 32 + fr * 16 + kslot * 4;
        int g = wc * 64 + fc * 16 + lr;
        v4f a = acc[fr][fc];
        ushort4 pk;
        pk.x = f2b(a[0]); pk.y = f2b(a[1]); pk.z = f2b(a[2]); pk.w = f2b(a[3]);
        *(ushort4*)&z1p[(size_t)g * Nx + m0] = pk;
        z1Tp[(size_t)(m0 + 0) * Gx + g] = pk.x;
        z1Tp[(size_t)(m0 + 1) * Gx + g] = pk.y;
        z1Tp[(size_t)(m0 + 2) * Gx + g] = pk.z;
        z1Tp[(size_t)(m0 + 3) * Gx + g] = pk.w;
      }
  } else if (MODE == 1) {
    u16* z2Tp = o1 + (size_t)bp * Nx * Gx;
#pragma unroll
    for (int fr = 0; fr < 2; fr++)
#pragma unroll
      for (int fc = 0; fc < 4; fc++) {
        int g0r = rt * 64 + wr * 32 + fr * 16 + kslot * 4;
        int m = ct * 128 + wc * 64 + fc * 16 + lr;
        v4f a = acc[fr][fc];
        ushort4 pk;
        pk.x = f2b(a[0]); pk.y = f2b(a[1]); pk.z = f2b(a[2]); pk.w = f2b(a[3]);
        *(ushort4*)&z2Tp[(size_t)m * Gx + g0r] = pk;
      }
  } else {
    float* op = oF + (size_t)(b * Px + p) * Fx * Nx;
#pragma unroll
    for (int fc = 0; fc < 4; fc++) {
      int f = wc * 64 + fc * 16 + lr;
      float bi = bias[f];
#pragma unroll
      for (int fr = 0; fr < 2; fr++) {
        int n0 = rt * 64 + wr * 32 + fr * 16 + kslot * 4;
        v4f a = acc[fr][fc];
        float4 o;
        o.x = fmaxf(a[0] + bi, 0.f);
        o.y = fmaxf(a[1] + bi, 0.f);
        o.z = fmaxf(a[2] + bi, 0.f);
        o.w = fmaxf(a[3] + bi, 0.f);
        *(float4*)&op[(size_t)f * Nx + n0] = o;
      }
    }
  }
}

// ---------------------------------------------------------------------------
extern "C" void kernel_launch(void* const* d_in, const int* in_sizes, int n_in,
                              void* d_out, int out_size, void* d_ws, size_t ws_size,
                              hipStream_t stream) {
  const float* x = (const float*)d_in[0];
  const float* S = (const float*)d_in[1];
  const float* W = (const float*)d_in[2];
  const float* h = (const float*)d_in[4];
  const float* bias = (const float*)d_in[5];
  float* out = (float*)d_out;

  char* ws = (char*)d_ws;
  u16* aijT  = (u16*)ws;                   // @ 0          33,554,432
  u16* WxT16 = (u16*)(ws + 33554432);      // @ 32M         8,388,608
  u16* xT16  = (u16*)(ws + 41943040);      // @ 40M         2,097,152
  u16* xTb   = (u16*)(ws + 44040192);      // @ 42M         2,097,152
  u16* xb    = (u16*)(ws + 46137344);      // @ 44M         2,097,152
  u16* z1    = (u16*)(ws + 48234496);      // @ 46M         8,388,608
  u16* z1T   = (u16*)(ws + 56623104);      // @ 54M         8,388,608
  u16* z2T   = (u16*)(ws + 65011712);      // @ 62M         8,388,608
  u16* Hb    = (u16*)(ws + 73400320);      // @ 70M           393,216
  u16* W16   = (u16*)(ws + 73793536);      //                 131,072
  u32* mb    = (u32*)(ws + 73924608);      //                 524,288

  prep_kernel<<<dim3(1792), 256, 0, stream>>>(S, x, W, h, mb, xb, xTb, xT16, W16, Hb);
  wxt16_kernel<<<dim3(Bx * Px, Nx / 64), 256, 0, stream>>>(xT16, W16, WxT16);
  attn4_kernel<<<dim3(Bx * Px, Nx / 64), 512, 0, stream>>>(xT16, WxT16, mb, aijT);
  gnt_kernel<0><<<dim3(Bx * Px, 8), 256, 0, stream>>>(aijT, xb, nullptr, nullptr,
                                                      z1, z1T, nullptr, nullptr);
  gnt_kernel<1><<<dim3(Bx * Px, 8), 256, 0, stream>>>(z1, aijT, nullptr, nullptr,
                                                      z2T, nullptr, nullptr, nullptr);
  gnt_kernel<2><<<dim3(Bx * Px, 8), 256, 0, stream>>>(xTb, z1T, z2T, Hb,
                                                      nullptr, nullptr, out, bias);
  (void)in_sizes; (void)n_in; (void)out_size; (void)ws_size;
}